// Round 4
// baseline (7987.927 us; speedup 1.0000x reference)
//
#include <hip/hip_runtime.h>
#include <hip/hip_bf16.h>
#include <stdint.h>

// Problem constants
#define TT   8192      // tokens = B*S
#define DD   2048      // d_model
#define FF   5632      // ffn hidden
#define EE   8         // experts
#define RR   16        // lora rank
#define NALL 11520     // F + F + E*2R = 5632+5632+256
#define NPAIR 16384    // T * TOPK

typedef float  f32x4  __attribute__((ext_vector_type(4)));
typedef __bf16 bf16x8 __attribute__((ext_vector_type(8)));
typedef __bf16 bf16x4 __attribute__((ext_vector_type(4)));

#define AS1CAST(p) ((__attribute__((address_space(1))) void*)(p))
#define AS3CAST(p) ((__attribute__((address_space(3))) void*)(p))

// ---------------------------------------------------------------------------
// f32 -> bf16 convert (float4 vectorized, grid-stride)
// ---------------------------------------------------------------------------
__global__ __launch_bounds__(256) void cvt_f32_bf16(const float* __restrict__ src,
                                                    __bf16* __restrict__ dst, int n4) {
    int stride = gridDim.x * 256;
    for (int i = blockIdx.x * 256 + threadIdx.x; i < n4; i += stride) {
        float4 v = ((const float4*)src)[i];
        bf16x4 o = {(__bf16)v.x, (__bf16)v.y, (__bf16)v.z, (__bf16)v.w};
        ((bf16x4*)dst)[i] = o;
    }
}

// Gather-convert A1/A3 into stacked rows [256][D]: row j=e*32+l, l<16 -> A1[e][l], else A3[e][l-16]
__global__ __launch_bounds__(256) void cvt_A13(const float* __restrict__ A1,
                                               const float* __restrict__ A3,
                                               __bf16* __restrict__ dst) {
    int i = blockIdx.x * 256 + threadIdx.x;   // [0, 256*512)
    int col4 = i & 511;                       // D/4 = 512
    int j = i >> 9;                           // row 0..255
    int e = j >> 5, l = j & 31;
    const float* src = (l < 16) ? (A1 + (size_t)(e * 16 + l) * DD)
                                : (A3 + (size_t)(e * 16 + (l - 16)) * DD);
    float4 v = ((const float4*)src)[col4];
    bf16x4 o = {(__bf16)v.x, (__bf16)v.y, (__bf16)v.z, (__bf16)v.w};
    ((bf16x4*)(dst + (size_t)j * DD))[col4] = o;
}

// A2 [E][R][F] fp32 -> A2t [E][F][R] bf16 (f-major, 16 contiguous bf16 per f)
__global__ __launch_bounds__(256) void cvt_A2t(const float* __restrict__ A2,
                                               __bf16* __restrict__ A2t) {
    int i = blockIdx.x * 256 + threadIdx.x;   // over E*RR*FF = 720896 exactly
    int f = i % FF;
    int r = (i / FF) % RR;
    int e = i / (FF * RR);
    A2t[((size_t)e * FF + f) * RR + r] = (__bf16)A2[i];
}

// ---------------------------------------------------------------------------
// Router: logits (fp32, output #2), top-2 renormalized weights per token
// ---------------------------------------------------------------------------
__global__ __launch_bounds__(256) void router_k(const float* __restrict__ x,
                                                const float* __restrict__ gw,
                                                float* __restrict__ logits,
                                                int* __restrict__ pair_e,
                                                float* __restrict__ pair_w) {
    int t = blockIdx.x * 4 + (threadIdx.x >> 6);
    int lane = threadIdx.x & 63;
    const float* xr = x + (size_t)t * DD;
    float acc[EE];
#pragma unroll
    for (int e = 0; e < EE; e++) acc[e] = 0.f;
    for (int d = lane; d < DD; d += 64) {
        float xv = xr[d];
#pragma unroll
        for (int e = 0; e < EE; e++) acc[e] += xv * gw[e * DD + d];
    }
#pragma unroll
    for (int off = 32; off > 0; off >>= 1) {
#pragma unroll
        for (int e = 0; e < EE; e++) acc[e] += __shfl_down(acc[e], off, 64);
    }
    if (lane == 0) {
        float mx = acc[0];
#pragma unroll
        for (int e = 1; e < EE; e++) mx = fmaxf(mx, acc[e]);
        float p[EE];
#pragma unroll
        for (int e = 0; e < EE; e++) p[e] = __expf(acc[e] - mx);
        int e0 = 0;
#pragma unroll
        for (int e = 1; e < EE; e++) if (p[e] > p[e0]) e0 = e;
        int e1 = (e0 == 0) ? 1 : 0;
#pragma unroll
        for (int e = 0; e < EE; e++) if (e != e0 && p[e] > p[e1]) e1 = e;
        float s = p[e0] + p[e1];
        pair_e[2 * t] = e0;     pair_e[2 * t + 1] = e1;
        pair_w[2 * t] = p[e0] / s; pair_w[2 * t + 1] = p[e1] / s;
#pragma unroll
        for (int e = 0; e < EE; e++) logits[(size_t)t * EE + e] = acc[e];
    }
}

// ---------------------------------------------------------------------------
// 256x256-tile 8-phase bf16 GEMM, B^T layout: C[M,N] = A[M,K] * B[N,K]^T.
// M,N multiples of 256; K multiple of 128.  512 threads = 8 waves (2Mx4N).
// LDS swizzle (FIXED this round): physical 16B-block index within each 128B
// row = logical ^ (row&7).  This spreads a wave's 16-row column-slice read
// across all 32 banks (8 accesses/bank = minimum); the old bit5^rowbit2
// swizzle provably left bank = f(col) only (16 accesses/bank) -> 1.7e7
// conflicts.  Applied on the staging GLOBAL source (global_load_lds writes
// linearly) and on the ds_read address (both-sides involution, rule #21).
// Counted vmcnt(4) once per K-tile; epilogue drains vmcnt to 0.
// ---------------------------------------------------------------------------
template <int OUT_BF16>
__global__ __launch_bounds__(512, 2) void gemm256(const __bf16* __restrict__ A,
                                                  const __bf16* __restrict__ B,
                                                  void* __restrict__ Cv,
                                                  int M, int N, int K) {
    __shared__ __align__(16) __bf16 lds[8][8192];   // [buf*4 + mat*2 + half][128*64]
    char* const sbase = (char*)&lds[0][0];
    const int tid = threadIdx.x;
    const int w = tid >> 6, lane = tid & 63;
    const int lrow = lane & 15, lq = lane >> 4;
    const int wr = w >> 2, wc = w & 3;

    // bijective XCD swizzle (m204): each XCD gets a contiguous chunk of tiles
    const int gx = gridDim.x;
    const int nwg = gx * gridDim.y;
    const int orig = blockIdx.x + blockIdx.y * gx;
    const int q8 = nwg >> 3, r8 = nwg & 7;
    const int xcd = orig & 7, sid = orig >> 3;
    const int nid = (xcd < r8 ? xcd * (q8 + 1) : r8 * (q8 + 1) + (xcd - r8) * q8) + sid;
    const int m0 = (nid % gx) * 256;
    const int n0 = (nid / gx) * 256;

    const size_t ldb = (size_t)K * 2;               // bytes per row
    // staging: wave w instr q covers phys rows w*16+q*8..+8, lane L writes 16B
    // at (row w*16+q*8+(L>>3), colblk L&7).  Inverse-swizzled source col:
    const int rq0 = w * 16 + (lane >> 3);
    const int cbs = (((lane & 7) ^ ((lane >> 3) & 7)) << 4);
    const char* gA0 = (const char*)A + (size_t)(m0 + rq0) * ldb + cbs;   // A half0
    const char* gA1 = gA0 + (size_t)128 * ldb;                            // A half1
    const char* gB0 = (const char*)B + (size_t)(n0 + rq0) * ldb + cbs;
    const char* gB1 = gB0 + (size_t)128 * ldb;
    const int wseg = w * 2048;

    // read geometry: logical col-block (ks*4+lq) -> physical ^ (lrow&7)
    const int aof0 = lrow * 128 + (((0 + lq) ^ (lrow & 7)) << 4);
    const int aof1 = lrow * 128 + (((4 + lq) ^ (lrow & 7)) << 4);
    const int bbase2 = ((wc & 1) * 64 + lrow) * 128;
    const int bof0 = bbase2 + (((0 + lq) ^ (lrow & 7)) << 4);
    const int bof1 = bbase2 + (((4 + lq) ^ (lrow & 7)) << 4);
    const int abuf = wr;             // A half this wave reads
    const int bbuf = 2 + (wc >> 1);  // B half this wave reads

    f32x4 acc[8][4] = {};
    bf16x8 aR[4][2], aS[4][2], bR[2][2], bS[2][2];

#define GLDS(gp, lo) __builtin_amdgcn_global_load_lds(AS1CAST((void*)(gp)), AS3CAST(sbase + (lo)), 16, 0, 0)
#define STAGEM(gp, bufmh) do { const char* _g = (gp); \
        GLDS(_g, (bufmh) * 16384 + wseg); \
        GLDS(_g + 8 * ldb, (bufmh) * 16384 + wseg + 1024); } while (0)
#define LDA_(c, i, of) (*(const bf16x8*)(sbase + ((c) * 4 + abuf) * 16384 + (i) * 2048 + (of)))
#define LDB_(c, j, of) (*(const bf16x8*)(sbase + ((c) * 4 + bbuf) * 16384 + (j) * 2048 + (of)))
#define MM(i, j, fa, fb) acc[i][j] = __builtin_amdgcn_mfma_f32_16x16x32_bf16(fa, fb, acc[i][j], 0, 0, 0)
#define PH_MID() do { __builtin_amdgcn_s_barrier(); \
        asm volatile("s_waitcnt lgkmcnt(0)" ::: "memory"); \
        __builtin_amdgcn_sched_barrier(0); \
        __builtin_amdgcn_s_setprio(1); } while (0)
#define PH_END() do { __builtin_amdgcn_s_setprio(0); \
        __builtin_amdgcn_s_barrier(); } while (0)

// 4 phases consuming buf c; stages: B halves of tile kBC -> buf c^1,
// then A halves of tile kAC -> buf c.  vmcnt(4) after 4th stage.
#define DO4(c, kBC, kAC) do { \
    _Pragma("unroll") for (int i = 0; i < 4; i++) { aR[i][0] = LDA_(c, i, aof0); aR[i][1] = LDA_(c, i, aof1); } \
    _Pragma("unroll") for (int j = 0; j < 2; j++) { bR[j][0] = LDB_(c, j, bof0); bR[j][1] = LDB_(c, j, bof1); } \
    STAGEM(gB0 + (size_t)(kBC) * 128, ((c) ^ 1) * 4 + 2); \
    PH_MID(); \
    _Pragma("unroll") for (int i = 0; i < 4; i++) \
    _Pragma("unroll") for (int j = 0; j < 2; j++) { MM(i, j, aR[i][0], bR[j][0]); MM(i, j, aR[i][1], bR[j][1]); } \
    PH_END(); \
    _Pragma("unroll") for (int i = 0; i < 4; i++) { aS[i][0] = LDA_(c, 4 + i, aof0); aS[i][1] = LDA_(c, 4 + i, aof1); } \
    STAGEM(gB1 + (size_t)(kBC) * 128, ((c) ^ 1) * 4 + 3); \
    PH_MID(); \
    _Pragma("unroll") for (int i = 0; i < 4; i++) \
    _Pragma("unroll") for (int j = 0; j < 2; j++) { MM(4 + i, j, aS[i][0], bR[j][0]); MM(4 + i, j, aS[i][1], bR[j][1]); } \
    PH_END(); \
    _Pragma("unroll") for (int j = 0; j < 2; j++) { bS[j][0] = LDB_(c, 2 + j, bof0); bS[j][1] = LDB_(c, 2 + j, bof1); } \
    STAGEM(gA0 + (size_t)(kAC) * 128, (c) * 4 + 0); \
    PH_MID(); \
    _Pragma("unroll") for (int i = 0; i < 4; i++) \
    _Pragma("unroll") for (int j = 0; j < 2; j++) { MM(i, 2 + j, aR[i][0], bS[j][0]); MM(i, 2 + j, aR[i][1], bS[j][1]); } \
    PH_END(); \
    STAGEM(gA1 + (size_t)(kAC) * 128, (c) * 4 + 1); \
    asm volatile("s_waitcnt vmcnt(4)" ::: "memory"); \
    PH_MID(); \
    _Pragma("unroll") for (int i = 0; i < 4; i++) \
    _Pragma("unroll") for (int j = 0; j < 2; j++) { MM(4 + i, 2 + j, aS[i][0], bS[j][0]); MM(4 + i, 2 + j, aS[i][1], bS[j][1]); } \
    PH_END(); \
} while (0)

    const int NT = K >> 6;        // 64-wide K-tiles (even: K % 128 == 0)
    const int NI = NT >> 1;

    // prologue: buf0 <- kt0 (A0,A1,B0,B1); buf1 <- kt1 (A halves).
    STAGEM(gA0, 0); STAGEM(gA1, 1); STAGEM(gB0, 2); STAGEM(gB1, 3);
    STAGEM(gA0 + 128, 4); STAGEM(gA1 + 128, 5);
    asm volatile("s_waitcnt vmcnt(4)" ::: "memory");
    __builtin_amdgcn_s_barrier();

    for (int it = 0; it < NI; it++) {
        int k2 = 2 * it + 2; if (k2 > NT - 1) k2 = NT - 1;   // clamped tail prefetch
        int k3 = 2 * it + 3; if (k3 > NT - 1) k3 = NT - 1;
        DO4(0, 2 * it + 1, k2);
        DO4(1, k2, k3);
    }

    // drain all in-flight global_load_lds before workgroup retires
    asm volatile("s_waitcnt vmcnt(0)" ::: "memory");

#undef DO4
#undef PH_END
#undef PH_MID
#undef MM
#undef LDB_
#undef LDA_
#undef STAGEM
#undef GLDS

    // epilogue: C/D layout col=lane&15, row=(lane>>4)*4+reg (m89-verified)
#pragma unroll
    for (int i = 0; i < 8; i++)
#pragma unroll
        for (int j = 0; j < 4; j++)
#pragma unroll
            for (int r = 0; r < 4; r++) {
                int row = m0 + wr * 128 + i * 16 + lq * 4 + r;
                int col = n0 + wc * 64 + j * 16 + lrow;
                float v = acc[i][j][r];
                if (OUT_BF16) ((__bf16*)Cv)[(size_t)row * N + col] = (__bf16)v;
                else          ((float*)Cv)[(size_t)row * N + col] = v;
            }
}

// ---------------------------------------------------------------------------
// g_build16: 16 tokens per block (4 waves x 4 tokens), expert tables staged
// in LDS per 64-wide f-chunk.  Table layout [m*2+h][e][f][8] (lo/hi split):
// lane=f reads are 16B blocks at stride 1 -> 8 accesses/bank (conflict-free).
// Cuts table traffic from 8.8 GB L2 (per-wave streaming) to 2.2 GB.
// Writes Gw[t][f] = w0*g0 + w1*g1 (bf16); GA[2t+k][r] = w_k * sum_f g_k*A2t.
// ---------------------------------------------------------------------------
__global__ __launch_bounds__(256, 2) void g_build16(const __bf16* __restrict__ base,
                                                    const __bf16* __restrict__ B1t,
                                                    const __bf16* __restrict__ B3t,
                                                    const __bf16* __restrict__ A2t,
                                                    const int* __restrict__ pair_e,
                                                    const float* __restrict__ pair_w,
                                                    __bf16* __restrict__ G,
                                                    float* __restrict__ GA,
                                                    int t0) {
    __shared__ __align__(16) __bf16 tb[6][EE][64][8];   // 49152 B
    const int tid = threadIdx.x, wave = tid >> 6, lane = tid & 63;
    const int lt0 = blockIdx.x * 16 + wave * 4;         // wave's first local token

    // wave-uniform routing data for the 4 tokens
    int e0k[4], e1k[4]; float w0k[4], w1k[4];
#pragma unroll
    for (int k = 0; k < 4; k++) {
        int t = t0 + lt0 + k;
        e0k[k] = pair_e[2 * t];     e1k[k] = pair_e[2 * t + 1];
        w0k[k] = pair_w[2 * t];     w1k[k] = pair_w[2 * t + 1];
    }

    float ga[4][2][16];
#pragma unroll
    for (int k = 0; k < 4; k++)
#pragma unroll
        for (int s = 0; s < 2; s++)
#pragma unroll
            for (int r = 0; r < 16; r++) ga[k][s][r] = 0.f;

    for (int fc = 0; fc < FF; fc += 64) {
        __syncthreads();   // previous chunk's reads complete before overwrite
#pragma unroll
        for (int it = 0; it < 12; it++) {
            int idx = it * 256 + tid;          // 0..3071
            int f = idx & 63;
            int e = (idx >> 6) & 7;
            int mh = idx >> 9;                 // 0..5 = m*2+h
            int m = mh >> 1, h = mh & 1;
            const __bf16* tp = (m == 0) ? B1t : (m == 1) ? B3t : A2t;
            *(bf16x8*)&tb[mh][e][f][0] =
                *(const bf16x8*)(tp + ((size_t)e * FF + (fc + f)) * RR + h * 8);
        }
        __syncthreads();

#pragma unroll
        for (int k = 0; k < 4; k++) {
            const __bf16* brow = base + (size_t)(lt0 + k) * NALL;
            const int e0 = e0k[k], e1 = e1k[k];
            // ha fragments (broadcast, L1/L2-cached)
            const bf16x8* pa = (const bf16x8*)(brow + 2 * FF + e0 * 32);
            const bf16x8* pb = (const bf16x8*)(brow + 2 * FF + e1 * 32);
            bf16x8 h1a0 = pa[0], h1a1 = pa[1], h3a0 = pa[2], h3a1 = pa[3];
            bf16x8 h1b0 = pb[0], h1b1 = pb[1], h3b0 = pb[2], h3b1 = pb[3];
            // table fragments from LDS (12 x b128, conflict-free)
            bf16x8 B1a0 = *(const bf16x8*)&tb[0][e0][lane][0];
            bf16x8 B1a1 = *(const bf16x8*)&tb[1][e0][lane][0];
            bf16x8 B3a0 = *(const bf16x8*)&tb[2][e0][lane][0];
            bf16x8 B3a1 = *(const bf16x8*)&tb[3][e0][lane][0];
            bf16x8 A2a0 = *(const bf16x8*)&tb[4][e0][lane][0];
            bf16x8 A2a1 = *(const bf16x8*)&tb[5][e0][lane][0];
            bf16x8 B1b0 = *(const bf16x8*)&tb[0][e1][lane][0];
            bf16x8 B1b1 = *(const bf16x8*)&tb[1][e1][lane][0];
            bf16x8 B3b0 = *(const bf16x8*)&tb[2][e1][lane][0];
            bf16x8 B3b1 = *(const bf16x8*)&tb[3][e1][lane][0];
            bf16x8 A2b0 = *(const bf16x8*)&tb[4][e1][lane][0];
            bf16x8 A2b1 = *(const bf16x8*)&tb[5][e1][lane][0];

            float bb1 = (float)brow[fc + lane];
            float bb3 = (float)brow[FF + fc + lane];
            float u1a = bb1, u3a = bb3, u1b = bb1, u3b = bb3;
#pragma unroll
            for (int r = 0; r < 8; r++) {
                u1a += (float)h1a0[r] * (float)B1a0[r] + (float)h1a1[r] * (float)B1a1[r];
                u3a += (float)h3a0[r] * (float)B3a0[r] + (float)h3a1[r] * (float)B3a1[r];
                u1b += (float)h1b0[r] * (float)B1b0[r] + (float)h1b1[r] * (float)B1b1[r];
                u3b += (float)h3b0[r] * (float)B3b0[r] + (float)h3b1[r] * (float)B3b1[r];
            }
            float g0 = (u1a / (1.f + __expf(-u1a))) * u3a;
            float g1 = (u1b / (1.f + __expf(-u1b))) * u3b;
            G[(size_t)(lt0 + k) * FF + fc + lane] = (__bf16)(w0k[k] * g0 + w1k[k] * g1);
#pragma unroll
            for (int r = 0; r < 8; r++) {
                ga[k][0][r]     += g0 * (float)A2a0[r];
                ga[k][0][8 + r] += g0 * (float)A2a1[r];
                ga[k][1][r]     += g1 * (float)A2b0[r];
                ga[k][1][8 + r] += g1 * (float)A2b1[r];
            }
        }
    }

#pragma unroll
    for (int off = 32; off > 0; off >>= 1)
#pragma unroll
        for (int k = 0; k < 4; k++)
#pragma unroll
            for (int r = 0; r < 16; r++) {
                ga[k][0][r] += __shfl_down(ga[k][0][r], off, 64);
                ga[k][1][r] += __shfl_down(ga[k][1][r], off, 64);
            }
    if (lane == 0) {
#pragma unroll
        for (int k = 0; k < 4; k++) {
            int t = t0 + lt0 + k;
#pragma unroll
            for (int r = 0; r < 16; r++) {
                GA[(size_t)(2 * t) * RR + r]     = w0k[k] * ga[k][0][r];
                GA[(size_t)(2 * t + 1) * RR + r] = w1k[k] * ga[k][1][r];
            }
        }
    }
}

// ---------------------------------------------------------------------------
// out[t,d] = Y[lt,d] + GA[2t]·B2[e0][d,:] + GA[2t+1]·B2[e1][d,:]
// ---------------------------------------------------------------------------
__global__ __launch_bounds__(256) void combine_k(const float* __restrict__ Y,
                                                 const float* __restrict__ GA,
                                                 const float* __restrict__ B2,
                                                 const int* __restrict__ pair_e,
                                                 float* __restrict__ out,
                                                 int t0) {
    const int lt = blockIdx.x;
    const int t = t0 + lt;
    const int tid = threadIdx.x;
    __shared__ float g0[RR], g1[RR];
    if (tid < 16) g0[tid] = GA[(size_t)(2 * t) * RR + tid];
    else if (tid < 32) g1[tid - 16] = GA[(size_t)(2 * t + 1) * RR + (tid - 16)];
    __syncthreads();
    const int e0 = pair_e[2 * t], e1 = pair_e[2 * t + 1];
    const float* B2e0 = B2 + (size_t)e0 * DD * RR;
    const float* B2e1 = B2 + (size_t)e1 * DD * RR;
    for (int d = tid; d < DD; d += 256) {
        float l0 = 0.f, l1 = 0.f;
        const float4* b0 = (const float4*)(B2e0 + (size_t)d * RR);
        const float4* b1 = (const float4*)(B2e1 + (size_t)d * RR);
#pragma unroll
        for (int q = 0; q < 4; q++) {
            float4 v0 = b0[q], v1 = b1[q];
            l0 += g0[q * 4 + 0] * v0.x + g0[q * 4 + 1] * v0.y + g0[q * 4 + 2] * v0.z + g0[q * 4 + 3] * v0.w;
            l1 += g1[q * 4 + 0] * v1.x + g1[q * 4 + 1] * v1.y + g1[q * 4 + 2] * v1.z + g1[q * 4 + 3] * v1.w;
        }
        out[(size_t)t * DD + d] = Y[(size_t)lt * DD + d] + l0 + l1;
    }
}

// ---------------------------------------------------------------------------
extern "C" void kernel_launch(void* const* d_in, const int* in_sizes, int n_in,
                              void* d_out, int out_size, void* d_ws, size_t ws_size,
                              hipStream_t stream) {
    const float* x  = (const float*)d_in[0];
    const float* gw = (const float*)d_in[1];
    const float* W1 = (const float*)d_in[2];
    const float* W3 = (const float*)d_in[3];
    const float* W2 = (const float*)d_in[4];
    const float* A1 = (const float*)d_in[5];
    const float* B1 = (const float*)d_in[6];
    const float* A3 = (const float*)d_in[7];
    const float* B3 = (const float*)d_in[8];
    const float* A2 = (const float*)d_in[9];
    const float* B2 = (const float*)d_in[10];

    float* out    = (float*)d_out;                 // [T*D]
    float* logits = out + (size_t)TT * DD;         // [T*E]

    char* ws = (char*)d_ws;
    size_t off = 0;
    auto carve = [&](size_t bytes) {
        char* p = ws + off;
        off += (bytes + 255) & ~(size_t)255;
        return p;
    };
    auto pad = [](size_t b) { return (b + 255) & ~(size_t)255; };

    // ---- persistent buffers ----
    __bf16* W2b   = (__bf16*)carve((size_t)DD * FF * 2);        // 23.1 MB
    __bf16* B1b   = (__bf16*)carve((size_t)EE * FF * RR * 2);   // 1.44 MB
    __bf16* B3b   = (__bf16*)carve((size_t)EE * FF * RR * 2);   // 1.44 MB
    __bf16* A2t   = (__bf16*)carve((size_t)EE * FF * RR * 2);   // 1.44 MB
    float*  GA    = (float*)carve((size_t)NPAIR * RR * 4);      // 1 MB
    int*    pair_e = (int*)carve((size_t)NPAIR * 4);
    float*  pair_w = (float*)carve((size_t)NPAIR * 4);
    // W_all and h_bf carved CONTIGUOUSLY so Y (67.1 MB fp32) overlays both
    // once the last GEMM1 chunk has consumed them (80.7 MB available).
    __bf16* W_all = (__bf16*)carve((size_t)NALL * DD * 2);      // 47.2 MB  rows: W1|W3|A13
    __bf16* h_bf  = (__bf16*)carve((size_t)TT * DD * 2);        // 33.6 MB
    float*  Y_full = (float*)W_all;
    size_t base0 = off;

    // ---- mode/chunk selection (deterministic per call) ----
    int C = 0, full = 0;
    {
        const int cand[6] = {8192, 4096, 2048, 1024, 512, 256};
        for (int ci = 0; ci < 6; ci++) {
            int c = cand[ci];
            size_t need = base0 + pad((size_t)TT * FF * 2) + pad((size_t)c * NALL * 2);
            if (need <= ws_size) { full = 1; C = c; break; }
        }
    }
    __bf16* Gbuf; __bf16* base_c; float* Y_c = nullptr;
    if (full) {
        Gbuf   = (__bf16*)carve((size_t)TT * FF * 2);           // 92.3 MB: combined G, all tokens
        base_c = (__bf16*)carve((size_t)C * NALL * 2);
    } else {
        // fallback: per-chunk pipeline (combined-G still halves GEMM2 flops)
        C = 2048;
        while (C > 256) {
            size_t need = base0 + pad((size_t)C * NALL * 2) + pad((size_t)C * FF * 2);
            if (need <= ws_size) break;
            C >>= 1;
        }
        base_c = (__bf16*)carve((size_t)C * NALL * 2);
        Gbuf   = (__bf16*)carve((size_t)C * FF * 2);
        Y_c    = (float*)base_c;     // C*D*4 <= C*NALL*2, base dead by then
    }

    // 1. converts (weights + full activation, once)
    cvt_f32_bf16<<<2048, 256, 0, stream>>>(x, h_bf, TT * DD / 4);
    cvt_f32_bf16<<<1024, 256, 0, stream>>>(W1, W_all, FF * DD / 4);
    cvt_f32_bf16<<<1024, 256, 0, stream>>>(W3, W_all + (size_t)FF * DD, FF * DD / 4);
    cvt_f32_bf16<<<1024, 256, 0, stream>>>(W2, W2b, DD * FF / 4);
    cvt_A13<<<512, 256, 0, stream>>>(A1, A3, W_all + (size_t)2 * FF * DD);
    cvt_f32_bf16<<<512, 256, 0, stream>>>(B1, B1b, EE * FF * RR / 4);
    cvt_f32_bf16<<<512, 256, 0, stream>>>(B3, B3b, EE * FF * RR / 4);
    cvt_A2t<<<EE * RR * FF / 256, 256, 0, stream>>>(A2, A2t);

    // 2. router (fp32) — writes logits output + pair routing
    router_k<<<TT / 4, 256, 0, stream>>>(x, gw, logits, pair_e, pair_w);

    // 3-4. up-projection + gate build (weight-combined G)
    for (int t0 = 0; t0 < TT; t0 += C) {
        gemm256<1><<<dim3(C / 256, NALL / 256), 512, 0, stream>>>(
            h_bf + (size_t)t0 * DD, W_all, base_c, C, NALL, DD);
        __bf16* Gp = full ? (Gbuf + (size_t)t0 * FF) : Gbuf;
        g_build16<<<C / 16, 256, 0, stream>>>(base_c, B1b, B3b, A2t, pair_e, pair_w, Gp, GA, t0);
        if (!full) {
            gemm256<0><<<dim3(C / 256, DD / 256), 512, 0, stream>>>(
                Gbuf, W2b, Y_c, C, DD, FF);
            combine_k<<<C, 256, 0, stream>>>(Y_c, GA, B2, pair_e, out, t0);
        }
    }

    // 5-6. one-shot down-projection over all tokens
    if (full) {
        gemm256<0><<<dim3(TT / 256, DD / 256), 512, 0, stream>>>(
            Gbuf, W2b, Y_full, TT, DD, FF);
        combine_k<<<TT, 256, 0, stream>>>(Y_full, GA, B2, pair_e, out, 0);
    }
}

// Round 5
// 1627.867 us; speedup vs baseline: 4.9070x; 4.9070x over previous
//
#include <hip/hip_runtime.h>
#include <hip/hip_bf16.h>
#include <stdint.h>

// Problem constants
#define TT   8192      // tokens = B*S
#define DD   2048      // d_model
#define FF   5632      // ffn hidden
#define EE   8         // experts
#define RR   16        // lora rank
#define NALL 11520     // F + F + E*2R = 5632+5632+256
#define NPAIR 16384    // T * TOPK

typedef float  f32x4  __attribute__((ext_vector_type(4)));
typedef __bf16 bf16x8 __attribute__((ext_vector_type(8)));
typedef __bf16 bf16x4 __attribute__((ext_vector_type(4)));

#define AS1CAST(p) ((__attribute__((address_space(1))) void*)(p))
#define AS3CAST(p) ((__attribute__((address_space(3))) void*)(p))

// ---------------------------------------------------------------------------
// f32 -> bf16 convert (float4 vectorized, grid-stride)
// ---------------------------------------------------------------------------
__global__ __launch_bounds__(256) void cvt_f32_bf16(const float* __restrict__ src,
                                                    __bf16* __restrict__ dst, int n4) {
    int stride = gridDim.x * 256;
    for (int i = blockIdx.x * 256 + threadIdx.x; i < n4; i += stride) {
        float4 v = ((const float4*)src)[i];
        bf16x4 o = {(__bf16)v.x, (__bf16)v.y, (__bf16)v.z, (__bf16)v.w};
        ((bf16x4*)dst)[i] = o;
    }
}

// Gather-convert A1/A3 into stacked rows [256][D]: row j=e*32+l, l<16 -> A1[e][l], else A3[e][l-16]
__global__ __launch_bounds__(256) void cvt_A13(const float* __restrict__ A1,
                                               const float* __restrict__ A3,
                                               __bf16* __restrict__ dst) {
    int i = blockIdx.x * 256 + threadIdx.x;   // [0, 256*512)
    int col4 = i & 511;                       // D/4 = 512
    int j = i >> 9;                           // row 0..255
    int e = j >> 5, l = j & 31;
    const float* src = (l < 16) ? (A1 + (size_t)(e * 16 + l) * DD)
                                : (A3 + (size_t)(e * 16 + (l - 16)) * DD);
    float4 v = ((const float4*)src)[col4];
    bf16x4 o = {(__bf16)v.x, (__bf16)v.y, (__bf16)v.z, (__bf16)v.w};
    ((bf16x4*)(dst + (size_t)j * DD))[col4] = o;
}

// A2 [E][R][F] fp32 -> A2t [E][F][R] bf16 (f-major, 16 contiguous bf16 per f)
__global__ __launch_bounds__(256) void cvt_A2t(const float* __restrict__ A2,
                                               __bf16* __restrict__ A2t) {
    int i = blockIdx.x * 256 + threadIdx.x;   // over E*RR*FF = 720896 exactly
    int f = i % FF;
    int r = (i / FF) % RR;
    int e = i / (FF * RR);
    A2t[((size_t)e * FF + f) * RR + r] = (__bf16)A2[i];
}

// ---------------------------------------------------------------------------
// Router: logits (fp32, output #2), top-2 renormalized weights per token
// ---------------------------------------------------------------------------
__global__ __launch_bounds__(256) void router_k(const float* __restrict__ x,
                                                const float* __restrict__ gw,
                                                float* __restrict__ logits,
                                                int* __restrict__ pair_e,
                                                float* __restrict__ pair_w) {
    int t = blockIdx.x * 4 + (threadIdx.x >> 6);
    int lane = threadIdx.x & 63;
    const float* xr = x + (size_t)t * DD;
    float acc[EE];
#pragma unroll
    for (int e = 0; e < EE; e++) acc[e] = 0.f;
    for (int d = lane; d < DD; d += 64) {
        float xv = xr[d];
#pragma unroll
        for (int e = 0; e < EE; e++) acc[e] += xv * gw[e * DD + d];
    }
#pragma unroll
    for (int off = 32; off > 0; off >>= 1) {
#pragma unroll
        for (int e = 0; e < EE; e++) acc[e] += __shfl_down(acc[e], off, 64);
    }
    if (lane == 0) {
        float mx = acc[0];
#pragma unroll
        for (int e = 1; e < EE; e++) mx = fmaxf(mx, acc[e]);
        float p[EE];
#pragma unroll
        for (int e = 0; e < EE; e++) p[e] = __expf(acc[e] - mx);
        int e0 = 0;
#pragma unroll
        for (int e = 1; e < EE; e++) if (p[e] > p[e0]) e0 = e;
        int e1 = (e0 == 0) ? 1 : 0;
#pragma unroll
        for (int e = 0; e < EE; e++) if (e != e0 && p[e] > p[e1]) e1 = e;
        float s = p[e0] + p[e1];
        pair_e[2 * t] = e0;     pair_e[2 * t + 1] = e1;
        pair_w[2 * t] = p[e0] / s; pair_w[2 * t + 1] = p[e1] / s;
#pragma unroll
        for (int e = 0; e < EE; e++) logits[(size_t)t * EE + e] = acc[e];
    }
}

// ---------------------------------------------------------------------------
// 256x256-tile 8-phase bf16 GEMM, B^T layout: C[M,N] = A[M,K] * B[N,K]^T.
// M,N multiples of 256; K multiple of 128.  512 threads = 8 waves (2Mx4N).
// LDS swizzle: physical 16B-block index within each 128B row = logical ^
// (row&7) -> a wave's 16-row column-slice read hits each bank exactly
// 8x (minimum).  Applied on the staging GLOBAL source (global_load_lds
// writes linearly) and on the ds_read address (both-sides involution).
// Counted vmcnt(4) once per K-tile; epilogue drains vmcnt to 0.
// ---------------------------------------------------------------------------
template <int OUT_BF16>
__global__ __launch_bounds__(512, 2) void gemm256(const __bf16* __restrict__ A,
                                                  const __bf16* __restrict__ B,
                                                  void* __restrict__ Cv,
                                                  int M, int N, int K) {
    __shared__ __align__(16) __bf16 lds[8][8192];   // [buf*4 + mat*2 + half][128*64]
    char* const sbase = (char*)&lds[0][0];
    const int tid = threadIdx.x;
    const int w = tid >> 6, lane = tid & 63;
    const int lrow = lane & 15, lq = lane >> 4;
    const int wr = w >> 2, wc = w & 3;

    // bijective XCD swizzle (m204): each XCD gets a contiguous chunk of tiles
    const int gx = gridDim.x;
    const int nwg = gx * gridDim.y;
    const int orig = blockIdx.x + blockIdx.y * gx;
    const int q8 = nwg >> 3, r8 = nwg & 7;
    const int xcd = orig & 7, sid = orig >> 3;
    const int nid = (xcd < r8 ? xcd * (q8 + 1) : r8 * (q8 + 1) + (xcd - r8) * q8) + sid;
    const int m0 = (nid % gx) * 256;
    const int n0 = (nid / gx) * 256;

    const size_t ldb = (size_t)K * 2;               // bytes per row
    // staging: wave w instr q covers phys rows w*16+q*8..+8, lane L writes 16B
    // at (row w*16+q*8+(L>>3), colblk L&7).  Inverse-swizzled source col:
    const int rq0 = w * 16 + (lane >> 3);
    const int cbs = (((lane & 7) ^ ((lane >> 3) & 7)) << 4);
    const char* gA0 = (const char*)A + (size_t)(m0 + rq0) * ldb + cbs;   // A half0
    const char* gA1 = gA0 + (size_t)128 * ldb;                            // A half1
    const char* gB0 = (const char*)B + (size_t)(n0 + rq0) * ldb + cbs;
    const char* gB1 = gB0 + (size_t)128 * ldb;
    const int wseg = w * 2048;

    // read geometry: logical col-block (ks*4+lq) -> physical ^ (lrow&7)
    const int aof0 = lrow * 128 + (((0 + lq) ^ (lrow & 7)) << 4);
    const int aof1 = lrow * 128 + (((4 + lq) ^ (lrow & 7)) << 4);
    const int bbase2 = ((wc & 1) * 64 + lrow) * 128;
    const int bof0 = bbase2 + (((0 + lq) ^ (lrow & 7)) << 4);
    const int bof1 = bbase2 + (((4 + lq) ^ (lrow & 7)) << 4);
    const int abuf = wr;             // A half this wave reads
    const int bbuf = 2 + (wc >> 1);  // B half this wave reads

    f32x4 acc[8][4] = {};
    bf16x8 aR[4][2], aS[4][2], bR[2][2], bS[2][2];

#define GLDS(gp, lo) __builtin_amdgcn_global_load_lds(AS1CAST((void*)(gp)), AS3CAST(sbase + (lo)), 16, 0, 0)
#define STAGEM(gp, bufmh) do { const char* _g = (gp); \
        GLDS(_g, (bufmh) * 16384 + wseg); \
        GLDS(_g + 8 * ldb, (bufmh) * 16384 + wseg + 1024); } while (0)
#define LDA_(c, i, of) (*(const bf16x8*)(sbase + ((c) * 4 + abuf) * 16384 + (i) * 2048 + (of)))
#define LDB_(c, j, of) (*(const bf16x8*)(sbase + ((c) * 4 + bbuf) * 16384 + (j) * 2048 + (of)))
#define MM(i, j, fa, fb) acc[i][j] = __builtin_amdgcn_mfma_f32_16x16x32_bf16(fa, fb, acc[i][j], 0, 0, 0)
#define PH_MID() do { __builtin_amdgcn_s_barrier(); \
        asm volatile("s_waitcnt lgkmcnt(0)" ::: "memory"); \
        __builtin_amdgcn_sched_barrier(0); \
        __builtin_amdgcn_s_setprio(1); } while (0)
#define PH_END() do { __builtin_amdgcn_s_setprio(0); \
        __builtin_amdgcn_s_barrier(); } while (0)

// 4 phases consuming buf c; stages: B halves of tile kBC -> buf c^1,
// then A halves of tile kAC -> buf c.  vmcnt(4) after 4th stage.
#define DO4(c, kBC, kAC) do { \
    _Pragma("unroll") for (int i = 0; i < 4; i++) { aR[i][0] = LDA_(c, i, aof0); aR[i][1] = LDA_(c, i, aof1); } \
    _Pragma("unroll") for (int j = 0; j < 2; j++) { bR[j][0] = LDB_(c, j, bof0); bR[j][1] = LDB_(c, j, bof1); } \
    STAGEM(gB0 + (size_t)(kBC) * 128, ((c) ^ 1) * 4 + 2); \
    PH_MID(); \
    _Pragma("unroll") for (int i = 0; i < 4; i++) \
    _Pragma("unroll") for (int j = 0; j < 2; j++) { MM(i, j, aR[i][0], bR[j][0]); MM(i, j, aR[i][1], bR[j][1]); } \
    PH_END(); \
    _Pragma("unroll") for (int i = 0; i < 4; i++) { aS[i][0] = LDA_(c, 4 + i, aof0); aS[i][1] = LDA_(c, 4 + i, aof1); } \
    STAGEM(gB1 + (size_t)(kBC) * 128, ((c) ^ 1) * 4 + 3); \
    PH_MID(); \
    _Pragma("unroll") for (int i = 0; i < 4; i++) \
    _Pragma("unroll") for (int j = 0; j < 2; j++) { MM(4 + i, j, aS[i][0], bR[j][0]); MM(4 + i, j, aS[i][1], bR[j][1]); } \
    PH_END(); \
    _Pragma("unroll") for (int j = 0; j < 2; j++) { bS[j][0] = LDB_(c, 2 + j, bof0); bS[j][1] = LDB_(c, 2 + j, bof1); } \
    STAGEM(gA0 + (size_t)(kAC) * 128, (c) * 4 + 0); \
    PH_MID(); \
    _Pragma("unroll") for (int i = 0; i < 4; i++) \
    _Pragma("unroll") for (int j = 0; j < 2; j++) { MM(i, 2 + j, aR[i][0], bS[j][0]); MM(i, 2 + j, aR[i][1], bS[j][1]); } \
    PH_END(); \
    STAGEM(gA1 + (size_t)(kAC) * 128, (c) * 4 + 1); \
    asm volatile("s_waitcnt vmcnt(4)" ::: "memory"); \
    PH_MID(); \
    _Pragma("unroll") for (int i = 0; i < 4; i++) \
    _Pragma("unroll") for (int j = 0; j < 2; j++) { MM(4 + i, 2 + j, aS[i][0], bS[j][0]); MM(4 + i, 2 + j, aS[i][1], bS[j][1]); } \
    PH_END(); \
} while (0)

    const int NT = K >> 6;        // 64-wide K-tiles (even: K % 128 == 0)
    const int NI = NT >> 1;

    // prologue: buf0 <- kt0 (A0,A1,B0,B1); buf1 <- kt1 (A halves).
    STAGEM(gA0, 0); STAGEM(gA1, 1); STAGEM(gB0, 2); STAGEM(gB1, 3);
    STAGEM(gA0 + 128, 4); STAGEM(gA1 + 128, 5);
    asm volatile("s_waitcnt vmcnt(4)" ::: "memory");
    __builtin_amdgcn_s_barrier();

    for (int it = 0; it < NI; it++) {
        int k2 = 2 * it + 2; if (k2 > NT - 1) k2 = NT - 1;   // clamped tail prefetch
        int k3 = 2 * it + 3; if (k3 > NT - 1) k3 = NT - 1;
        DO4(0, 2 * it + 1, k2);
        DO4(1, k2, k3);
    }

    // drain all in-flight global_load_lds before workgroup retires
    asm volatile("s_waitcnt vmcnt(0)" ::: "memory");

#undef DO4
#undef PH_END
#undef PH_MID
#undef MM
#undef LDB_
#undef LDA_
#undef STAGEM
#undef GLDS

    // epilogue: C/D layout col=lane&15, row=(lane>>4)*4+reg (m89-verified)
#pragma unroll
    for (int i = 0; i < 8; i++)
#pragma unroll
        for (int j = 0; j < 4; j++)
#pragma unroll
            for (int r = 0; r < 4; r++) {
                int row = m0 + wr * 128 + i * 16 + lq * 4 + r;
                int col = n0 + wc * 64 + j * 16 + lrow;
                float v = acc[i][j][r];
                if (OUT_BF16) ((__bf16*)Cv)[(size_t)row * N + col] = (__bf16)v;
                else          ((float*)Cv)[(size_t)row * N + col] = v;
            }
}

// ---------------------------------------------------------------------------
// g_build_tok: one TOKEN per wave (both routed experts in one pass).
// (reverted from g_build16: 128 accumulators/thread spilled to scratch ->
//  30x slowdown.  This version keeps 32 accumulators/thread, no spill.)
// Writes Gw[t][f] = w0*g0 + w1*g1 (bf16); GA[2t+k][r] = w_k * sum_f g_k*A2t.
// ---------------------------------------------------------------------------
__global__ __launch_bounds__(256) void g_build_tok(const __bf16* __restrict__ base,
                                                   const __bf16* __restrict__ B1t,
                                                   const __bf16* __restrict__ B3t,
                                                   const __bf16* __restrict__ A2t,
                                                   const int* __restrict__ pair_e,
                                                   const float* __restrict__ pair_w,
                                                   __bf16* __restrict__ G,
                                                   float* __restrict__ GA,
                                                   int t0) {
    const int wave = threadIdx.x >> 6, lane = threadIdx.x & 63;
    const int lt = blockIdx.x * 4 + wave;     // local token in chunk
    const int t = t0 + lt;                    // global token
    const int e0 = pair_e[2 * t], e1 = pair_e[2 * t + 1];
    const float w0 = pair_w[2 * t], w1 = pair_w[2 * t + 1];
    const __bf16* brow = base + (size_t)lt * NALL;

    float ha1a[16], ha3a[16], ha1b[16], ha3b[16];
    {
        const bf16x8* pa = (const bf16x8*)(brow + 2 * FF + e0 * 32);
        const bf16x8* pb = (const bf16x8*)(brow + 2 * FF + e1 * 32);
        bf16x8 a0 = pa[0], a1 = pa[1], a2v = pa[2], a3v = pa[3];
        bf16x8 b0 = pb[0], b1v = pb[1], b2v = pb[2], b3v = pb[3];
#pragma unroll
        for (int r = 0; r < 8; r++) {
            ha1a[r] = (float)a0[r];  ha1a[8 + r] = (float)a1[r];
            ha3a[r] = (float)a2v[r]; ha3a[8 + r] = (float)a3v[r];
            ha1b[r] = (float)b0[r];  ha1b[8 + r] = (float)b1v[r];
            ha3b[r] = (float)b2v[r]; ha3b[8 + r] = (float)b3v[r];
        }
    }
    const __bf16* B1a = B1t + (size_t)e0 * FF * RR;
    const __bf16* B3a = B3t + (size_t)e0 * FF * RR;
    const __bf16* A2a = A2t + (size_t)e0 * FF * RR;
    const __bf16* B1b = B1t + (size_t)e1 * FF * RR;
    const __bf16* B3b = B3t + (size_t)e1 * FF * RR;
    const __bf16* A2b = A2t + (size_t)e1 * FF * RR;
    __bf16* Grow = G + (size_t)lt * FF;

    float ga0[16], ga1[16];
#pragma unroll
    for (int r = 0; r < 16; r++) { ga0[r] = 0.f; ga1[r] = 0.f; }

    for (int f = lane; f < FF; f += 64) {
        const size_t fo = (size_t)f * RR;
        const bf16x8* p;
        p = (const bf16x8*)(B1a + fo); bf16x8 b1l = p[0], b1h = p[1];
        p = (const bf16x8*)(B3a + fo); bf16x8 b3l = p[0], b3h = p[1];
        p = (const bf16x8*)(B1b + fo); bf16x8 c1l = p[0], c1h = p[1];
        p = (const bf16x8*)(B3b + fo); bf16x8 c3l = p[0], c3h = p[1];
        float bb1 = (float)brow[f], bb3 = (float)brow[FF + f];
        float u1a = bb1, u3a = bb3, u1b = bb1, u3b = bb3;
#pragma unroll
        for (int r = 0; r < 8; r++) {
            u1a += ha1a[r] * (float)b1l[r] + ha1a[8 + r] * (float)b1h[r];
            u3a += ha3a[r] * (float)b3l[r] + ha3a[8 + r] * (float)b3h[r];
            u1b += ha1b[r] * (float)c1l[r] + ha1b[8 + r] * (float)c1h[r];
            u3b += ha3b[r] * (float)c3l[r] + ha3b[8 + r] * (float)c3h[r];
        }
        float g0 = (u1a / (1.f + __expf(-u1a))) * u3a;
        float g1 = (u1b / (1.f + __expf(-u1b))) * u3b;
        Grow[f] = (__bf16)(w0 * g0 + w1 * g1);
        p = (const bf16x8*)(A2a + fo); bf16x8 a2l = p[0], a2h = p[1];
        p = (const bf16x8*)(A2b + fo); bf16x8 a4l = p[0], a4h = p[1];
#pragma unroll
        for (int r = 0; r < 8; r++) {
            ga0[r]     += g0 * (float)a2l[r];
            ga0[8 + r] += g0 * (float)a2h[r];
            ga1[r]     += g1 * (float)a4l[r];
            ga1[8 + r] += g1 * (float)a4h[r];
        }
    }
#pragma unroll
    for (int off = 32; off > 0; off >>= 1) {
#pragma unroll
        for (int r = 0; r < 16; r++) {
            ga0[r] += __shfl_down(ga0[r], off, 64);
            ga1[r] += __shfl_down(ga1[r], off, 64);
        }
    }
    if (lane == 0) {
#pragma unroll
        for (int r = 0; r < 16; r++) {
            GA[(size_t)(2 * t) * RR + r]     = w0 * ga0[r];
            GA[(size_t)(2 * t + 1) * RR + r] = w1 * ga1[r];
        }
    }
}

// ---------------------------------------------------------------------------
// out[t,d] = Y[lt,d] + GA[2t]·B2[e0][d,:] + GA[2t+1]·B2[e1][d,:]
// ---------------------------------------------------------------------------
__global__ __launch_bounds__(256) void combine_k(const float* __restrict__ Y,
                                                 const float* __restrict__ GA,
                                                 const float* __restrict__ B2,
                                                 const int* __restrict__ pair_e,
                                                 float* __restrict__ out,
                                                 int t0) {
    const int lt = blockIdx.x;
    const int t = t0 + lt;
    const int tid = threadIdx.x;
    __shared__ float g0[RR], g1[RR];
    if (tid < 16) g0[tid] = GA[(size_t)(2 * t) * RR + tid];
    else if (tid < 32) g1[tid - 16] = GA[(size_t)(2 * t + 1) * RR + (tid - 16)];
    __syncthreads();
    const int e0 = pair_e[2 * t], e1 = pair_e[2 * t + 1];
    const float* B2e0 = B2 + (size_t)e0 * DD * RR;
    const float* B2e1 = B2 + (size_t)e1 * DD * RR;
    for (int d = tid; d < DD; d += 256) {
        float l0 = 0.f, l1 = 0.f;
        const float4* b0 = (const float4*)(B2e0 + (size_t)d * RR);
        const float4* b1 = (const float4*)(B2e1 + (size_t)d * RR);
#pragma unroll
        for (int q = 0; q < 4; q++) {
            float4 v0 = b0[q], v1 = b1[q];
            l0 += g0[q * 4 + 0] * v0.x + g0[q * 4 + 1] * v0.y + g0[q * 4 + 2] * v0.z + g0[q * 4 + 3] * v0.w;
            l1 += g1[q * 4 + 0] * v1.x + g1[q * 4 + 1] * v1.y + g1[q * 4 + 2] * v1.z + g1[q * 4 + 3] * v1.w;
        }
        out[(size_t)t * DD + d] = Y[(size_t)lt * DD + d] + l0 + l1;
    }
}

// ---------------------------------------------------------------------------
extern "C" void kernel_launch(void* const* d_in, const int* in_sizes, int n_in,
                              void* d_out, int out_size, void* d_ws, size_t ws_size,
                              hipStream_t stream) {
    const float* x  = (const float*)d_in[0];
    const float* gw = (const float*)d_in[1];
    const float* W1 = (const float*)d_in[2];
    const float* W3 = (const float*)d_in[3];
    const float* W2 = (const float*)d_in[4];
    const float* A1 = (const float*)d_in[5];
    const float* B1 = (const float*)d_in[6];
    const float* A3 = (const float*)d_in[7];
    const float* B3 = (const float*)d_in[8];
    const float* A2 = (const float*)d_in[9];
    const float* B2 = (const float*)d_in[10];

    float* out    = (float*)d_out;                 // [T*D]
    float* logits = out + (size_t)TT * DD;         // [T*E]

    char* ws = (char*)d_ws;
    size_t off = 0;
    auto carve = [&](size_t bytes) {
        char* p = ws + off;
        off += (bytes + 255) & ~(size_t)255;
        return p;
    };
    auto pad = [](size_t b) { return (b + 255) & ~(size_t)255; };

    // ---- persistent buffers ----
    __bf16* W2b   = (__bf16*)carve((size_t)DD * FF * 2);        // 23.1 MB
    __bf16* B1b   = (__bf16*)carve((size_t)EE * FF * RR * 2);   // 1.44 MB
    __bf16* B3b   = (__bf16*)carve((size_t)EE * FF * RR * 2);   // 1.44 MB
    __bf16* A2t   = (__bf16*)carve((size_t)EE * FF * RR * 2);   // 1.44 MB
    float*  GA    = (float*)carve((size_t)NPAIR * RR * 4);      // 1 MB
    int*    pair_e = (int*)carve((size_t)NPAIR * 4);
    float*  pair_w = (float*)carve((size_t)NPAIR * 4);
    // W_all and h_bf carved CONTIGUOUSLY so Y (67.1 MB fp32) overlays both
    // once the last GEMM1 chunk has consumed them (80.7 MB available).
    __bf16* W_all = (__bf16*)carve((size_t)NALL * DD * 2);      // 47.2 MB  rows: W1|W3|A13
    __bf16* h_bf  = (__bf16*)carve((size_t)TT * DD * 2);        // 33.6 MB
    float*  Y_full = (float*)W_all;
    size_t base0 = off;

    // ---- mode/chunk selection (deterministic per call) ----
    int C = 0, full = 0;
    {
        const int cand[6] = {8192, 4096, 2048, 1024, 512, 256};
        for (int ci = 0; ci < 6; ci++) {
            int c = cand[ci];
            size_t need = base0 + pad((size_t)TT * FF * 2) + pad((size_t)c * NALL * 2);
            if (need <= ws_size) { full = 1; C = c; break; }
        }
    }
    __bf16* Gbuf; __bf16* base_c; float* Y_c = nullptr;
    if (full) {
        Gbuf   = (__bf16*)carve((size_t)TT * FF * 2);           // 92.3 MB: combined G, all tokens
        base_c = (__bf16*)carve((size_t)C * NALL * 2);
    } else {
        // fallback: per-chunk pipeline (combined-G still halves GEMM2 flops)
        C = 2048;
        while (C > 256) {
            size_t need = base0 + pad((size_t)C * NALL * 2) + pad((size_t)C * FF * 2);
            if (need <= ws_size) break;
            C >>= 1;
        }
        base_c = (__bf16*)carve((size_t)C * NALL * 2);
        Gbuf   = (__bf16*)carve((size_t)C * FF * 2);
        Y_c    = (float*)base_c;     // C*D*4 <= C*NALL*2, base dead by then
    }

    // 1. converts (weights + full activation, once)
    cvt_f32_bf16<<<2048, 256, 0, stream>>>(x, h_bf, TT * DD / 4);
    cvt_f32_bf16<<<1024, 256, 0, stream>>>(W1, W_all, FF * DD / 4);
    cvt_f32_bf16<<<1024, 256, 0, stream>>>(W3, W_all + (size_t)FF * DD, FF * DD / 4);
    cvt_f32_bf16<<<1024, 256, 0, stream>>>(W2, W2b, DD * FF / 4);
    cvt_A13<<<512, 256, 0, stream>>>(A1, A3, W_all + (size_t)2 * FF * DD);
    cvt_f32_bf16<<<512, 256, 0, stream>>>(B1, B1b, EE * FF * RR / 4);
    cvt_f32_bf16<<<512, 256, 0, stream>>>(B3, B3b, EE * FF * RR / 4);
    cvt_A2t<<<EE * RR * FF / 256, 256, 0, stream>>>(A2, A2t);

    // 2. router (fp32) — writes logits output + pair routing
    router_k<<<TT / 4, 256, 0, stream>>>(x, gw, logits, pair_e, pair_w);

    // 3-4. up-projection + gate build (weight-combined G)
    for (int t0 = 0; t0 < TT; t0 += C) {
        gemm256<1><<<dim3(C / 256, NALL / 256), 512, 0, stream>>>(
            h_bf + (size_t)t0 * DD, W_all, base_c, C, NALL, DD);
        __bf16* Gp = full ? (Gbuf + (size_t)t0 * FF) : Gbuf;
        g_build_tok<<<C / 4, 256, 0, stream>>>(base_c, B1b, B3b, A2t, pair_e, pair_w, Gp, GA, t0);
        if (!full) {
            gemm256<0><<<dim3(C / 256, DD / 256), 512, 0, stream>>>(
                Gbuf, W2b, Y_c, C, DD, FF);
            combine_k<<<C, 256, 0, stream>>>(Y_c, GA, B2, pair_e, out, t0);
        }
    }

    // 5-6. one-shot down-projection over all tokens
    if (full) {
        gemm256<0><<<dim3(TT / 256, DD / 256), 512, 0, stream>>>(
            Gbuf, W2b, Y_full, TT, DD, FF);
        combine_k<<<TT, 256, 0, stream>>>(Y_full, GA, B2, pair_e, out, 0);
    }
}

// Round 6
// 1353.388 us; speedup vs baseline: 5.9022x; 1.2028x over previous
//
#include <hip/hip_runtime.h>
#include <hip/hip_bf16.h>
#include <stdint.h>

// Problem constants
#define TT   8192      // tokens = B*S
#define DD   2048      // d_model
#define FF   5632      // ffn hidden
#define EE   8         // experts
#define RR   16        // lora rank
#define NALL 11520     // F + F + E*2R = 5632+5632+256
#define NPAIR 16384    // T * TOPK

typedef float  f32x4  __attribute__((ext_vector_type(4)));
typedef __bf16 bf16x8 __attribute__((ext_vector_type(8)));
typedef __bf16 bf16x4 __attribute__((ext_vector_type(4)));

#define AS1CAST(p) ((__attribute__((address_space(1))) void*)(p))
#define AS3CAST(p) ((__attribute__((address_space(3))) void*)(p))

// ---------------------------------------------------------------------------
// f32 -> bf16 convert (float4 vectorized, grid-stride)
// ---------------------------------------------------------------------------
__global__ __launch_bounds__(256) void cvt_f32_bf16(const float* __restrict__ src,
                                                    __bf16* __restrict__ dst, int n4) {
    int stride = gridDim.x * 256;
    for (int i = blockIdx.x * 256 + threadIdx.x; i < n4; i += stride) {
        float4 v = ((const float4*)src)[i];
        bf16x4 o = {(__bf16)v.x, (__bf16)v.y, (__bf16)v.z, (__bf16)v.w};
        ((bf16x4*)dst)[i] = o;
    }
}

// Gather-convert A1/A3 into stacked rows [256][D]: row j=e*32+l, l<16 -> A1[e][l], else A3[e][l-16]
__global__ __launch_bounds__(256) void cvt_A13(const float* __restrict__ A1,
                                               const float* __restrict__ A3,
                                               __bf16* __restrict__ dst) {
    int i = blockIdx.x * 256 + threadIdx.x;   // [0, 256*512)
    int col4 = i & 511;                       // D/4 = 512
    int j = i >> 9;                           // row 0..255
    int e = j >> 5, l = j & 31;
    const float* src = (l < 16) ? (A1 + (size_t)(e * 16 + l) * DD)
                                : (A3 + (size_t)(e * 16 + (l - 16)) * DD);
    float4 v = ((const float4*)src)[col4];
    bf16x4 o = {(__bf16)v.x, (__bf16)v.y, (__bf16)v.z, (__bf16)v.w};
    ((bf16x4*)(dst + (size_t)j * DD))[col4] = o;
}

// A2 [E][R][F] fp32 -> A2t [E][F][R] bf16 (f-major, 16 contiguous bf16 per f)
__global__ __launch_bounds__(256) void cvt_A2t(const float* __restrict__ A2,
                                               __bf16* __restrict__ A2t) {
    int i = blockIdx.x * 256 + threadIdx.x;   // over E*RR*FF = 720896 exactly
    int f = i % FF;
    int r = (i / FF) % RR;
    int e = i / (FF * RR);
    A2t[((size_t)e * FF + f) * RR + r] = (__bf16)A2[i];
}

// ---------------------------------------------------------------------------
// Router: logits (fp32, output #2), top-2 renormalized weights per token
// ---------------------------------------------------------------------------
__global__ __launch_bounds__(256) void router_k(const float* __restrict__ x,
                                                const float* __restrict__ gw,
                                                float* __restrict__ logits,
                                                int* __restrict__ pair_e,
                                                float* __restrict__ pair_w) {
    int t = blockIdx.x * 4 + (threadIdx.x >> 6);
    int lane = threadIdx.x & 63;
    const float* xr = x + (size_t)t * DD;
    float acc[EE];
#pragma unroll
    for (int e = 0; e < EE; e++) acc[e] = 0.f;
    for (int d = lane; d < DD; d += 64) {
        float xv = xr[d];
#pragma unroll
        for (int e = 0; e < EE; e++) acc[e] += xv * gw[e * DD + d];
    }
#pragma unroll
    for (int off = 32; off > 0; off >>= 1) {
#pragma unroll
        for (int e = 0; e < EE; e++) acc[e] += __shfl_down(acc[e], off, 64);
    }
    if (lane == 0) {
        float mx = acc[0];
#pragma unroll
        for (int e = 1; e < EE; e++) mx = fmaxf(mx, acc[e]);
        float p[EE];
#pragma unroll
        for (int e = 0; e < EE; e++) p[e] = __expf(acc[e] - mx);
        int e0 = 0;
#pragma unroll
        for (int e = 1; e < EE; e++) if (p[e] > p[e0]) e0 = e;
        int e1 = (e0 == 0) ? 1 : 0;
#pragma unroll
        for (int e = 0; e < EE; e++) if (e != e0 && p[e] > p[e1]) e1 = e;
        float s = p[e0] + p[e1];
        pair_e[2 * t] = e0;     pair_e[2 * t + 1] = e1;
        pair_w[2 * t] = p[e0] / s; pair_w[2 * t + 1] = p[e1] / s;
#pragma unroll
        for (int e = 0; e < EE; e++) logits[(size_t)t * EE + e] = acc[e];
    }
}

// ---------------------------------------------------------------------------
// 256x256-tile 8-phase bf16 GEMM, B^T layout: C[M,N] = A[M,K] * B[N,K]^T.
// M,N multiples of 256; K multiple of 128.  512 threads = 8 waves (2Mx4N).
// Swizzle: ROUND-3 form (measured fastest): byte ^= ((row>>2)&1)<<5 — mild
// 32B-pair permutation of the global source keeps the DMA coalescer happy;
// residual ~2x LDS conflicts are cheaper than a scrambled source (round-5
// A/B: full per-row permute -> 0 conflicts but +21% time).
// MODE 1: store bf16 C.  MODE 2: fused epilogue writes
//   out[t][col] = acc + GA[2t]·B2[e0][col,:] + GA[2t+1]·B2[e1][col,:]
// (replaces the separate combine_k kernel; saves Y write+read round-trip).
// Counted vmcnt(4) once per K-tile; epilogue drains vmcnt to 0.
// ---------------------------------------------------------------------------
template <int MODE>
__global__ __launch_bounds__(512, 2) void gemm256(const __bf16* __restrict__ A,
                                                  const __bf16* __restrict__ B,
                                                  void* __restrict__ Cv,
                                                  int M, int N, int K,
                                                  const float* __restrict__ GA,
                                                  const float* __restrict__ B2,
                                                  const int* __restrict__ pe,
                                                  int tbase) {
    __shared__ __align__(16) __bf16 lds[8][8192];   // [buf*4 + mat*2 + half][128*64]
    char* const sbase = (char*)&lds[0][0];
    const int tid = threadIdx.x;
    const int w = tid >> 6, lane = tid & 63;
    const int lrow = lane & 15, lq = lane >> 4;
    const int wr = w >> 2, wc = w & 3;

    // bijective XCD swizzle (m204): each XCD gets a contiguous chunk of tiles
    const int gx = gridDim.x;
    const int nwg = gx * gridDim.y;
    const int orig = blockIdx.x + blockIdx.y * gx;
    const int q8 = nwg >> 3, r8 = nwg & 7;
    const int xcd = orig & 7, sid = orig >> 3;
    const int nid = (xcd < r8 ? xcd * (q8 + 1) : r8 * (q8 + 1) + (xcd - r8) * q8) + sid;
    const int m0 = (nid % gx) * 256;
    const int n0 = (nid / gx) * 256;

    const size_t ldb = (size_t)K * 2;               // bytes per row
    // staging: wave w instr q covers phys rows w*16+q*8..+8, lane L writes 16B
    // at (row w*16+q*8+(L>>3), colblk L&7).  Inverse-swizzled source col:
    const int rq0 = w * 16 + (lane >> 3);
    const int cbs = ((lane & 7) * 16) ^ (((rq0 >> 2) & 1) << 5);
    const char* gA0 = (const char*)A + (size_t)(m0 + rq0) * ldb + cbs;   // A half0
    const char* gA1 = gA0 + (size_t)128 * ldb;                            // A half1
    const char* gB0 = (const char*)B + (size_t)(n0 + rq0) * ldb + cbs;
    const char* gB1 = gB0 + (size_t)128 * ldb;
    const int wseg = w * 2048;

    // read geometry (swizzle bit is thread-constant: row bit2 == lrow bit2)
    const int sb = ((lrow >> 2) & 1) << 5;
    const int aoff = lrow * 128 + ((lq * 16) ^ sb);
    const int boff = ((wc & 1) * 64 + lrow) * 128 + ((lq * 16) ^ sb);
    const int abuf = wr;             // A half this wave reads
    const int bbuf = 2 + (wc >> 1);  // B half this wave reads

    f32x4 acc[8][4] = {};
    bf16x8 aR[4][2], aS[4][2], bR[2][2], bS[2][2];

#define GLDS(gp, lo) __builtin_amdgcn_global_load_lds(AS1CAST((void*)(gp)), AS3CAST(sbase + (lo)), 16, 0, 0)
#define STAGEM(gp, bufmh) do { const char* _g = (gp); \
        GLDS(_g, (bufmh) * 16384 + wseg); \
        GLDS(_g + 8 * ldb, (bufmh) * 16384 + wseg + 1024); } while (0)
#define LDAf(c, i, ks) (*(const bf16x8*)(sbase + ((c) * 4 + abuf) * 16384 + aoff + (i) * 2048 + (ks) * 64))
#define LDBf(c, j, ks) (*(const bf16x8*)(sbase + ((c) * 4 + bbuf) * 16384 + boff + (j) * 2048 + (ks) * 64))
#define MM(i, j, fa, fb) acc[i][j] = __builtin_amdgcn_mfma_f32_16x16x32_bf16(fa, fb, acc[i][j], 0, 0, 0)
#define PH_MID() do { __builtin_amdgcn_s_barrier(); \
        asm volatile("s_waitcnt lgkmcnt(0)" ::: "memory"); \
        __builtin_amdgcn_sched_barrier(0); \
        __builtin_amdgcn_s_setprio(1); } while (0)
#define PH_END() do { __builtin_amdgcn_s_setprio(0); \
        __builtin_amdgcn_s_barrier(); } while (0)

// 4 phases consuming buf c; stages: B halves of tile kBC -> buf c^1,
// then A halves of tile kAC -> buf c.  vmcnt(4) after 4th stage.
#define DO4(c, kBC, kAC) do { \
    _Pragma("unroll") for (int i = 0; i < 4; i++) { aR[i][0] = LDAf(c, i, 0); aR[i][1] = LDAf(c, i, 1); } \
    _Pragma("unroll") for (int j = 0; j < 2; j++) { bR[j][0] = LDBf(c, j, 0); bR[j][1] = LDBf(c, j, 1); } \
    STAGEM(gB0 + (size_t)(kBC) * 128, ((c) ^ 1) * 4 + 2); \
    PH_MID(); \
    _Pragma("unroll") for (int i = 0; i < 4; i++) \
    _Pragma("unroll") for (int j = 0; j < 2; j++) { MM(i, j, aR[i][0], bR[j][0]); MM(i, j, aR[i][1], bR[j][1]); } \
    PH_END(); \
    _Pragma("unroll") for (int i = 0; i < 4; i++) { aS[i][0] = LDAf(c, 4 + i, 0); aS[i][1] = LDAf(c, 4 + i, 1); } \
    STAGEM(gB1 + (size_t)(kBC) * 128, ((c) ^ 1) * 4 + 3); \
    PH_MID(); \
    _Pragma("unroll") for (int i = 0; i < 4; i++) \
    _Pragma("unroll") for (int j = 0; j < 2; j++) { MM(4 + i, j, aS[i][0], bR[j][0]); MM(4 + i, j, aS[i][1], bR[j][1]); } \
    PH_END(); \
    _Pragma("unroll") for (int j = 0; j < 2; j++) { bS[j][0] = LDBf(c, 2 + j, 0); bS[j][1] = LDBf(c, 2 + j, 1); } \
    STAGEM(gA0 + (size_t)(kAC) * 128, (c) * 4 + 0); \
    PH_MID(); \
    _Pragma("unroll") for (int i = 0; i < 4; i++) \
    _Pragma("unroll") for (int j = 0; j < 2; j++) { MM(i, 2 + j, aR[i][0], bS[j][0]); MM(i, 2 + j, aR[i][1], bS[j][1]); } \
    PH_END(); \
    STAGEM(gA1 + (size_t)(kAC) * 128, (c) * 4 + 1); \
    asm volatile("s_waitcnt vmcnt(4)" ::: "memory"); \
    PH_MID(); \
    _Pragma("unroll") for (int i = 0; i < 4; i++) \
    _Pragma("unroll") for (int j = 0; j < 2; j++) { MM(4 + i, 2 + j, aS[i][0], bS[j][0]); MM(4 + i, 2 + j, aS[i][1], bS[j][1]); } \
    PH_END(); \
} while (0)

    const int NT = K >> 6;        // 64-wide K-tiles (even: K % 128 == 0)
    const int NI = NT >> 1;

    // prologue: buf0 <- kt0 (A0,A1,B0,B1); buf1 <- kt1 (A halves).
    STAGEM(gA0, 0); STAGEM(gA1, 1); STAGEM(gB0, 2); STAGEM(gB1, 3);
    STAGEM(gA0 + 128, 4); STAGEM(gA1 + 128, 5);
    asm volatile("s_waitcnt vmcnt(4)" ::: "memory");
    __builtin_amdgcn_s_barrier();

    for (int it = 0; it < NI; it++) {
        int k2 = 2 * it + 2; if (k2 > NT - 1) k2 = NT - 1;   // clamped tail prefetch
        int k3 = 2 * it + 3; if (k3 > NT - 1) k3 = NT - 1;
        DO4(0, 2 * it + 1, k2);
        DO4(1, k2, k3);
    }

    // drain all in-flight global_load_lds before workgroup retires
    asm volatile("s_waitcnt vmcnt(0)" ::: "memory");

#undef DO4
#undef PH_END
#undef PH_MID
#undef MM
#undef LDBf
#undef LDAf
#undef STAGEM
#undef GLDS

    // epilogue: C/D layout col=lane&15, row=(lane>>4)*4+reg (m89-verified)
    if (MODE == 1) {
#pragma unroll
        for (int i = 0; i < 8; i++)
#pragma unroll
            for (int j = 0; j < 4; j++)
#pragma unroll
                for (int r = 0; r < 4; r++) {
                    int row = m0 + wr * 128 + i * 16 + lq * 4 + r;
                    int col = n0 + wc * 64 + j * 16 + lrow;
                    ((__bf16*)Cv)[(size_t)row * N + col] = (__bf16)acc[i][j][r];
                }
    } else {
        // fused combine: out[t][col] = acc + GA[2t]·B2[e0] + GA[2t+1]·B2[e1]
#pragma unroll
        for (int i = 0; i < 8; i++) {
#pragma unroll
            for (int r = 0; r < 4; r++) {
                const int row = m0 + wr * 128 + i * 16 + lq * 4 + r;
                const int t = tbase + row;
                const int e0 = pe[2 * t], e1 = pe[2 * t + 1];
                const float4* g0p = (const float4*)(GA + (size_t)(2 * t) * RR);
                const float4* g1p = (const float4*)(GA + (size_t)(2 * t + 1) * RR);
                float4 ga0[4] = {g0p[0], g0p[1], g0p[2], g0p[3]};
                float4 ga1[4] = {g1p[0], g1p[1], g1p[2], g1p[3]};
                const float* B2e0 = B2 + (size_t)e0 * DD * RR;
                const float* B2e1 = B2 + (size_t)e1 * DD * RR;
#pragma unroll
                for (int j = 0; j < 4; j++) {
                    const int col = n0 + wc * 64 + j * 16 + lrow;
                    float l = acc[i][j][r];
                    const float4* b0 = (const float4*)(B2e0 + (size_t)col * RR);
                    const float4* b1 = (const float4*)(B2e1 + (size_t)col * RR);
#pragma unroll
                    for (int q = 0; q < 4; q++) {
                        float4 v0 = b0[q], v1 = b1[q];
                        l += ga0[q].x * v0.x + ga0[q].y * v0.y + ga0[q].z * v0.z + ga0[q].w * v0.w;
                        l += ga1[q].x * v1.x + ga1[q].y * v1.y + ga1[q].z * v1.z + ga1[q].w * v1.w;
                    }
                    ((float*)Cv)[(size_t)t * N + col] = l;
                }
            }
        }
    }
}

// ---------------------------------------------------------------------------
// g_build_tok: one TOKEN per wave (both routed experts in one pass).
// 32 accumulator regs/thread — no spill (the 16-token variant spilled, r4).
// Writes Gw[t][f] = w0*g0 + w1*g1 (bf16); GA[2t+k][r] = w_k * sum_f g_k*A2t.
// ---------------------------------------------------------------------------
__global__ __launch_bounds__(256) void g_build_tok(const __bf16* __restrict__ base,
                                                   const __bf16* __restrict__ B1t,
                                                   const __bf16* __restrict__ B3t,
                                                   const __bf16* __restrict__ A2t,
                                                   const int* __restrict__ pair_e,
                                                   const float* __restrict__ pair_w,
                                                   __bf16* __restrict__ G,
                                                   float* __restrict__ GA,
                                                   int t0) {
    const int wave = threadIdx.x >> 6, lane = threadIdx.x & 63;
    const int lt = blockIdx.x * 4 + wave;     // local token in chunk
    const int t = t0 + lt;                    // global token
    const int e0 = pair_e[2 * t], e1 = pair_e[2 * t + 1];
    const float w0 = pair_w[2 * t], w1 = pair_w[2 * t + 1];
    const __bf16* brow = base + (size_t)lt * NALL;

    float ha1a[16], ha3a[16], ha1b[16], ha3b[16];
    {
        const bf16x8* pa = (const bf16x8*)(brow + 2 * FF + e0 * 32);
        const bf16x8* pb = (const bf16x8*)(brow + 2 * FF + e1 * 32);
        bf16x8 a0 = pa[0], a1 = pa[1], a2v = pa[2], a3v = pa[3];
        bf16x8 b0 = pb[0], b1v = pb[1], b2v = pb[2], b3v = pb[3];
#pragma unroll
        for (int r = 0; r < 8; r++) {
            ha1a[r] = (float)a0[r];  ha1a[8 + r] = (float)a1[r];
            ha3a[r] = (float)a2v[r]; ha3a[8 + r] = (float)a3v[r];
            ha1b[r] = (float)b0[r];  ha1b[8 + r] = (float)b1v[r];
            ha3b[r] = (float)b2v[r]; ha3b[8 + r] = (float)b3v[r];
        }
    }
    const __bf16* B1a = B1t + (size_t)e0 * FF * RR;
    const __bf16* B3a = B3t + (size_t)e0 * FF * RR;
    const __bf16* A2a = A2t + (size_t)e0 * FF * RR;
    const __bf16* B1b = B1t + (size_t)e1 * FF * RR;
    const __bf16* B3b = B3t + (size_t)e1 * FF * RR;
    const __bf16* A2b = A2t + (size_t)e1 * FF * RR;
    __bf16* Grow = G + (size_t)lt * FF;

    float ga0[16], ga1[16];
#pragma unroll
    for (int r = 0; r < 16; r++) { ga0[r] = 0.f; ga1[r] = 0.f; }

    for (int f = lane; f < FF; f += 64) {
        const size_t fo = (size_t)f * RR;
        const bf16x8* p;
        p = (const bf16x8*)(B1a + fo); bf16x8 b1l = p[0], b1h = p[1];
        p = (const bf16x8*)(B3a + fo); bf16x8 b3l = p[0], b3h = p[1];
        p = (const bf16x8*)(B1b + fo); bf16x8 c1l = p[0], c1h = p[1];
        p = (const bf16x8*)(B3b + fo); bf16x8 c3l = p[0], c3h = p[1];
        float bb1 = (float)brow[f], bb3 = (float)brow[FF + f];
        float u1a = bb1, u3a = bb3, u1b = bb1, u3b = bb3;
#pragma unroll
        for (int r = 0; r < 8; r++) {
            u1a += ha1a[r] * (float)b1l[r] + ha1a[8 + r] * (float)b1h[r];
            u3a += ha3a[r] * (float)b3l[r] + ha3a[8 + r] * (float)b3h[r];
            u1b += ha1b[r] * (float)c1l[r] + ha1b[8 + r] * (float)c1h[r];
            u3b += ha3b[r] * (float)c3l[r] + ha3b[8 + r] * (float)c3h[r];
        }
        float g0 = (u1a / (1.f + __expf(-u1a))) * u3a;
        float g1 = (u1b / (1.f + __expf(-u1b))) * u3b;
        Grow[f] = (__bf16)(w0 * g0 + w1 * g1);
        p = (const bf16x8*)(A2a + fo); bf16x8 a2l = p[0], a2h = p[1];
        p = (const bf16x8*)(A2b + fo); bf16x8 a4l = p[0], a4h = p[1];
#pragma unroll
        for (int r = 0; r < 8; r++) {
            ga0[r]     += g0 * (float)a2l[r];
            ga0[8 + r] += g0 * (float)a2h[r];
            ga1[r]     += g1 * (float)a4l[r];
            ga1[8 + r] += g1 * (float)a4h[r];
        }
    }
#pragma unroll
    for (int off = 32; off > 0; off >>= 1) {
#pragma unroll
        for (int r = 0; r < 16; r++) {
            ga0[r] += __shfl_down(ga0[r], off, 64);
            ga1[r] += __shfl_down(ga1[r], off, 64);
        }
    }
    if (lane == 0) {
#pragma unroll
        for (int r = 0; r < 16; r++) {
            GA[(size_t)(2 * t) * RR + r]     = w0 * ga0[r];
            GA[(size_t)(2 * t + 1) * RR + r] = w1 * ga1[r];
        }
    }
}

// ---------------------------------------------------------------------------
extern "C" void kernel_launch(void* const* d_in, const int* in_sizes, int n_in,
                              void* d_out, int out_size, void* d_ws, size_t ws_size,
                              hipStream_t stream) {
    const float* x  = (const float*)d_in[0];
    const float* gw = (const float*)d_in[1];
    const float* W1 = (const float*)d_in[2];
    const float* W3 = (const float*)d_in[3];
    const float* W2 = (const float*)d_in[4];
    const float* A1 = (const float*)d_in[5];
    const float* B1 = (const float*)d_in[6];
    const float* A3 = (const float*)d_in[7];
    const float* B3 = (const float*)d_in[8];
    const float* A2 = (const float*)d_in[9];
    const float* B2 = (const float*)d_in[10];

    float* out    = (float*)d_out;                 // [T*D]
    float* logits = out + (size_t)TT * DD;         // [T*E]

    char* ws = (char*)d_ws;
    size_t off = 0;
    auto carve = [&](size_t bytes) {
        char* p = ws + off;
        off += (bytes + 255) & ~(size_t)255;
        return p;
    };
    auto pad = [](size_t b) { return (b + 255) & ~(size_t)255; };

    // ---- persistent small buffers ----
    __bf16* B1b   = (__bf16*)carve((size_t)EE * FF * RR * 2);   // 1.44 MB
    __bf16* B3b   = (__bf16*)carve((size_t)EE * FF * RR * 2);   // 1.44 MB
    __bf16* A2t   = (__bf16*)carve((size_t)EE * FF * RR * 2);   // 1.44 MB
    float*  GA    = (float*)carve((size_t)NPAIR * RR * 4);      // 1 MB
    int*    pair_e = (int*)carve((size_t)NPAIR * 4);
    float*  pair_w = (float*)carve((size_t)NPAIR * 4);
    // WREG: W_all (W1|W3|A13 bf16, 47.2 MB) during GEMM1; after the last
    // GEMM1 chunk it is dead and W2b (23.1 MB) is converted into it (full mode).
    char*   WREG  = carve((size_t)NALL * DD * 2);
    __bf16* W_all = (__bf16*)WREG;
    size_t base0 = off;

    // ---- mode/chunk selection (deterministic per call) ----
    // full mode: Gbuf (all tokens) + per-chunk h_c/base_c; combine fused into
    // GEMM2 epilogue so no Y buffer is needed.
    int C = 0, full = 0;
    {
        const int cand[5] = {4096, 2048, 1024, 512, 256};
        for (int ci = 0; ci < 5; ci++) {
            int c = cand[ci];
            size_t need = base0 + pad((size_t)TT * FF * 2)
                        + pad((size_t)c * DD * 2) + pad((size_t)c * NALL * 2);
            if (need <= ws_size) { full = 1; C = c; break; }
        }
    }
    __bf16* Gbuf = nullptr; __bf16* base_c; __bf16* h_c; __bf16* W2b; __bf16* G_c = nullptr;
    if (full) {
        Gbuf   = (__bf16*)carve((size_t)TT * FF * 2);           // 92.3 MB
        h_c    = (__bf16*)carve((size_t)C * DD * 2);
        base_c = (__bf16*)carve((size_t)C * NALL * 2);
        W2b    = (__bf16*)WREG;                                 // converted post-GEMM1
    } else {
        // fallback: per-chunk pipeline with fused GEMM2 epilogue
        W2b = (__bf16*)carve((size_t)DD * FF * 2);              // 23.1 MB
        C = 2048;
        while (C > 256) {
            size_t need = off + pad((size_t)C * DD * 2)
                        + pad((size_t)C * NALL * 2) + pad((size_t)C * FF * 2);
            if (need <= ws_size) break;
            C >>= 1;
        }
        h_c    = (__bf16*)carve((size_t)C * DD * 2);
        base_c = (__bf16*)carve((size_t)C * NALL * 2);
        G_c    = (__bf16*)carve((size_t)C * FF * 2);
    }

    // 1. weight converts (once)
    cvt_f32_bf16<<<1024, 256, 0, stream>>>(W1, W_all, FF * DD / 4);
    cvt_f32_bf16<<<1024, 256, 0, stream>>>(W3, W_all + (size_t)FF * DD, FF * DD / 4);
    cvt_A13<<<512, 256, 0, stream>>>(A1, A3, W_all + (size_t)2 * FF * DD);
    cvt_f32_bf16<<<512, 256, 0, stream>>>(B1, B1b, EE * FF * RR / 4);
    cvt_f32_bf16<<<512, 256, 0, stream>>>(B3, B3b, EE * FF * RR / 4);
    cvt_A2t<<<EE * RR * FF / 256, 256, 0, stream>>>(A2, A2t);
    if (!full) cvt_f32_bf16<<<1024, 256, 0, stream>>>(W2, W2b, DD * FF / 4);

    // 2. router (fp32) — writes logits output + pair routing
    router_k<<<TT / 4, 256, 0, stream>>>(x, gw, logits, pair_e, pair_w);

    // 3-4. chunked: x convert + up-projection + gate build (weight-combined G)
    for (int t0 = 0; t0 < TT; t0 += C) {
        cvt_f32_bf16<<<1024, 256, 0, stream>>>(x + (size_t)t0 * DD, h_c, C * DD / 4);
        gemm256<1><<<dim3(C / 256, NALL / 256), 512, 0, stream>>>(
            h_c, W_all, base_c, C, NALL, DD, nullptr, nullptr, nullptr, 0);
        __bf16* Gp = full ? (Gbuf + (size_t)t0 * FF) : G_c;
        g_build_tok<<<C / 4, 256, 0, stream>>>(base_c, B1b, B3b, A2t, pair_e, pair_w, Gp, GA, t0);
        if (!full) {
            gemm256<2><<<dim3(C / 256, DD / 256), 512, 0, stream>>>(
                G_c, W2b, out, C, DD, FF, GA, B2, pair_e, t0);
        }
    }

    // 5. one-shot down-projection with fused combine (grid 32x8 = 1 block/CU)
    if (full) {
        cvt_f32_bf16<<<1024, 256, 0, stream>>>(W2, W2b, DD * FF / 4);  // into WREG (W_all dead)
        gemm256<2><<<dim3(TT / 256, DD / 256), 512, 0, stream>>>(
            Gbuf, W2b, out, TT, DD, FF, GA, B2, pair_e, 0);
    }
}

// Round 7
// 1243.057 us; speedup vs baseline: 6.4260x; 1.0888x over previous
//
#include <hip/hip_runtime.h>
#include <hip/hip_bf16.h>
#include <stdint.h>

// Problem constants
#define TT   8192      // tokens = B*S
#define DD   2048      // d_model
#define FF   5632      // ffn hidden
#define EE   8         // experts
#define RR   16        // lora rank
#define NALL 11520     // F + F + E*2R = 5632+5632+256
#define KE   5760      // FF + EE*RR: extended K for fused down-projection
#define NPAIR 16384    // T * TOPK

typedef float  f32x4  __attribute__((ext_vector_type(4)));
typedef __bf16 bf16x8 __attribute__((ext_vector_type(8)));
typedef __bf16 bf16x4 __attribute__((ext_vector_type(4)));

#define AS1CAST(p) ((__attribute__((address_space(1))) void*)(p))
#define AS3CAST(p) ((__attribute__((address_space(3))) void*)(p))

// ---------------------------------------------------------------------------
// f32 -> bf16 convert (float4 vectorized, grid-stride)
// ---------------------------------------------------------------------------
__global__ __launch_bounds__(256) void cvt_f32_bf16(const float* __restrict__ src,
                                                    __bf16* __restrict__ dst, int n4) {
    int stride = gridDim.x * 256;
    for (int i = blockIdx.x * 256 + threadIdx.x; i < n4; i += stride) {
        float4 v = ((const float4*)src)[i];
        bf16x4 o = {(__bf16)v.x, (__bf16)v.y, (__bf16)v.z, (__bf16)v.w};
        ((bf16x4*)dst)[i] = o;
    }
}

// Gather-convert A1/A3 into stacked rows [256][D]: row j=e*32+l, l<16 -> A1[e][l], else A3[e][l-16]
__global__ __launch_bounds__(256) void cvt_A13(const float* __restrict__ A1,
                                               const float* __restrict__ A3,
                                               __bf16* __restrict__ dst) {
    int i = blockIdx.x * 256 + threadIdx.x;   // [0, 256*512)
    int col4 = i & 511;                       // D/4 = 512
    int j = i >> 9;                           // row 0..255
    int e = j >> 5, l = j & 31;
    const float* src = (l < 16) ? (A1 + (size_t)(e * 16 + l) * DD)
                                : (A3 + (size_t)(e * 16 + (l - 16)) * DD);
    float4 v = ((const float4*)src)[col4];
    bf16x4 o = {(__bf16)v.x, (__bf16)v.y, (__bf16)v.z, (__bf16)v.w};
    ((bf16x4*)(dst + (size_t)j * DD))[col4] = o;
}

// A2 [E][R][F] fp32 -> A2t [E][F][R] bf16 (f-major, 16 contiguous bf16 per f)
__global__ __launch_bounds__(256) void cvt_A2t(const float* __restrict__ A2,
                                               __bf16* __restrict__ A2t) {
    int i = blockIdx.x * 256 + threadIdx.x;   // over E*RR*FF = 720896 exactly
    int f = i % FF;
    int r = (i / FF) % RR;
    int e = i / (FF * RR);
    A2t[((size_t)e * FF + f) * RR + r] = (__bf16)A2[i];
}

// W2ext [D][KE] bf16: row d = [W2[d][0..FF) | B2[e][d][r] for e*16+r in 0..128)
__global__ __launch_bounds__(256) void cvt_W2ext(const float* __restrict__ W2,
                                                 const float* __restrict__ B2,
                                                 __bf16* __restrict__ dst) {
    const int n4 = DD * KE / 4;
    int stride = gridDim.x * 256;
    for (int i = blockIdx.x * 256 + threadIdx.x; i < n4; i += stride) {
        int j = (i % (KE / 4)) * 4;           // col (multiple of 4)
        int d = i / (KE / 4);
        float4 v;
        if (j < FF) {
            v = *(const float4*)(W2 + (size_t)d * FF + j);
        } else {
            int o = j - FF;                   // 0..127, multiple of 4 -> same expert block
            int e = o >> 4, r = o & 15;
            const float* b = B2 + ((size_t)e * DD + d) * RR + r;
            v.x = b[0]; v.y = b[1]; v.z = b[2]; v.w = b[3];
        }
        bf16x4 o4 = {(__bf16)v.x, (__bf16)v.y, (__bf16)v.z, (__bf16)v.w};
        ((bf16x4*)dst)[i] = o4;
    }
}

// ---------------------------------------------------------------------------
// Router: logits (fp32, output #2), top-2 renormalized weights per token
// ---------------------------------------------------------------------------
__global__ __launch_bounds__(256) void router_k(const float* __restrict__ x,
                                                const float* __restrict__ gw,
                                                float* __restrict__ logits,
                                                int* __restrict__ pair_e,
                                                float* __restrict__ pair_w) {
    int t = blockIdx.x * 4 + (threadIdx.x >> 6);
    int lane = threadIdx.x & 63;
    const float* xr = x + (size_t)t * DD;
    float acc[EE];
#pragma unroll
    for (int e = 0; e < EE; e++) acc[e] = 0.f;
    for (int d = lane; d < DD; d += 64) {
        float xv = xr[d];
#pragma unroll
        for (int e = 0; e < EE; e++) acc[e] += xv * gw[e * DD + d];
    }
#pragma unroll
    for (int off = 32; off > 0; off >>= 1) {
#pragma unroll
        for (int e = 0; e < EE; e++) acc[e] += __shfl_down(acc[e], off, 64);
    }
    if (lane == 0) {
        float mx = acc[0];
#pragma unroll
        for (int e = 1; e < EE; e++) mx = fmaxf(mx, acc[e]);
        float p[EE];
#pragma unroll
        for (int e = 0; e < EE; e++) p[e] = __expf(acc[e] - mx);
        int e0 = 0;
#pragma unroll
        for (int e = 1; e < EE; e++) if (p[e] > p[e0]) e0 = e;
        int e1 = (e0 == 0) ? 1 : 0;
#pragma unroll
        for (int e = 0; e < EE; e++) if (e != e0 && p[e] > p[e1]) e1 = e;
        float s = p[e0] + p[e1];
        pair_e[2 * t] = e0;     pair_e[2 * t + 1] = e1;
        pair_w[2 * t] = p[e0] / s; pair_w[2 * t + 1] = p[e1] / s;
#pragma unroll
        for (int e = 0; e < EE; e++) logits[(size_t)t * EE + e] = acc[e];
    }
}

// ---------------------------------------------------------------------------
// 256x256-tile 8-phase bf16 GEMM, B^T layout: C[M,N] = A[M,K] * B[N,K]^T.
// M,N multiples of 256; K multiple of 128.  512 threads = 8 waves (2Mx4N).
// Swizzle: round-3 form (measured fastest): byte ^= ((row>>2)&1)<<5 on both
// the staging global source and the ds_read address.  (Round-5 A/B: the full
// per-row permute zeroed conflicts but scrambled the DMA source, +21% time.)
// Plain epilogue only (fused-combine epilogue cost +125us at 1 block/CU, r6).
// Counted vmcnt(4) once per K-tile; epilogue drains vmcnt to 0.
// ---------------------------------------------------------------------------
template <int OUT_BF16>
__global__ __launch_bounds__(512, 2) void gemm256(const __bf16* __restrict__ A,
                                                  const __bf16* __restrict__ B,
                                                  void* __restrict__ Cv,
                                                  int M, int N, int K) {
    __shared__ __align__(16) __bf16 lds[8][8192];   // [buf*4 + mat*2 + half][128*64]
    char* const sbase = (char*)&lds[0][0];
    const int tid = threadIdx.x;
    const int w = tid >> 6, lane = tid & 63;
    const int lrow = lane & 15, lq = lane >> 4;
    const int wr = w >> 2, wc = w & 3;

    // bijective XCD swizzle (m204): each XCD gets a contiguous chunk of tiles
    const int gx = gridDim.x;
    const int nwg = gx * gridDim.y;
    const int orig = blockIdx.x + blockIdx.y * gx;
    const int q8 = nwg >> 3, r8 = nwg & 7;
    const int xcd = orig & 7, sid = orig >> 3;
    const int nid = (xcd < r8 ? xcd * (q8 + 1) : r8 * (q8 + 1) + (xcd - r8) * q8) + sid;
    const int m0 = (nid % gx) * 256;
    const int n0 = (nid / gx) * 256;

    const size_t ldb = (size_t)K * 2;               // bytes per row
    // staging: wave w instr q covers phys rows w*16+q*8..+8, lane L writes 16B
    // at (row w*16+q*8+(L>>3), colblk L&7).  Inverse-swizzled source col:
    const int rq0 = w * 16 + (lane >> 3);
    const int cbs = ((lane & 7) * 16) ^ (((rq0 >> 2) & 1) << 5);
    const char* gA0 = (const char*)A + (size_t)(m0 + rq0) * ldb + cbs;   // A half0
    const char* gA1 = gA0 + (size_t)128 * ldb;                            // A half1
    const char* gB0 = (const char*)B + (size_t)(n0 + rq0) * ldb + cbs;
    const char* gB1 = gB0 + (size_t)128 * ldb;
    const int wseg = w * 2048;

    // read geometry (swizzle bit is thread-constant: row bit2 == lrow bit2)
    const int sb = ((lrow >> 2) & 1) << 5;
    const int aoff = lrow * 128 + ((lq * 16) ^ sb);
    const int boff = ((wc & 1) * 64 + lrow) * 128 + ((lq * 16) ^ sb);
    const int abuf = wr;             // A half this wave reads
    const int bbuf = 2 + (wc >> 1);  // B half this wave reads

    f32x4 acc[8][4] = {};
    bf16x8 aR[4][2], aS[4][2], bR[2][2], bS[2][2];

#define GLDS(gp, lo) __builtin_amdgcn_global_load_lds(AS1CAST((void*)(gp)), AS3CAST(sbase + (lo)), 16, 0, 0)
#define STAGEM(gp, bufmh) do { const char* _g = (gp); \
        GLDS(_g, (bufmh) * 16384 + wseg); \
        GLDS(_g + 8 * ldb, (bufmh) * 16384 + wseg + 1024); } while (0)
#define LDAf(c, i, ks) (*(const bf16x8*)(sbase + ((c) * 4 + abuf) * 16384 + aoff + (i) * 2048 + (ks) * 64))
#define LDBf(c, j, ks) (*(const bf16x8*)(sbase + ((c) * 4 + bbuf) * 16384 + boff + (j) * 2048 + (ks) * 64))
#define MM(i, j, fa, fb) acc[i][j] = __builtin_amdgcn_mfma_f32_16x16x32_bf16(fa, fb, acc[i][j], 0, 0, 0)
#define PH_MID() do { __builtin_amdgcn_s_barrier(); \
        asm volatile("s_waitcnt lgkmcnt(0)" ::: "memory"); \
        __builtin_amdgcn_sched_barrier(0); \
        __builtin_amdgcn_s_setprio(1); } while (0)
#define PH_END() do { __builtin_amdgcn_s_setprio(0); \
        __builtin_amdgcn_s_barrier(); } while (0)

// 4 phases consuming buf c; stages: B halves of tile kBC -> buf c^1,
// then A halves of tile kAC -> buf c.  vmcnt(4) after 4th stage.
#define DO4(c, kBC, kAC) do { \
    _Pragma("unroll") for (int i = 0; i < 4; i++) { aR[i][0] = LDAf(c, i, 0); aR[i][1] = LDAf(c, i, 1); } \
    _Pragma("unroll") for (int j = 0; j < 2; j++) { bR[j][0] = LDBf(c, j, 0); bR[j][1] = LDBf(c, j, 1); } \
    STAGEM(gB0 + (size_t)(kBC) * 128, ((c) ^ 1) * 4 + 2); \
    PH_MID(); \
    _Pragma("unroll") for (int i = 0; i < 4; i++) \
    _Pragma("unroll") for (int j = 0; j < 2; j++) { MM(i, j, aR[i][0], bR[j][0]); MM(i, j, aR[i][1], bR[j][1]); } \
    PH_END(); \
    _Pragma("unroll") for (int i = 0; i < 4; i++) { aS[i][0] = LDAf(c, 4 + i, 0); aS[i][1] = LDAf(c, 4 + i, 1); } \
    STAGEM(gB1 + (size_t)(kBC) * 128, ((c) ^ 1) * 4 + 3); \
    PH_MID(); \
    _Pragma("unroll") for (int i = 0; i < 4; i++) \
    _Pragma("unroll") for (int j = 0; j < 2; j++) { MM(4 + i, j, aS[i][0], bR[j][0]); MM(4 + i, j, aS[i][1], bR[j][1]); } \
    PH_END(); \
    _Pragma("unroll") for (int j = 0; j < 2; j++) { bS[j][0] = LDBf(c, 2 + j, 0); bS[j][1] = LDBf(c, 2 + j, 1); } \
    STAGEM(gA0 + (size_t)(kAC) * 128, (c) * 4 + 0); \
    PH_MID(); \
    _Pragma("unroll") for (int i = 0; i < 4; i++) \
    _Pragma("unroll") for (int j = 0; j < 2; j++) { MM(i, 2 + j, aR[i][0], bS[j][0]); MM(i, 2 + j, aR[i][1], bS[j][1]); } \
    PH_END(); \
    STAGEM(gA1 + (size_t)(kAC) * 128, (c) * 4 + 1); \
    asm volatile("s_waitcnt vmcnt(4)" ::: "memory"); \
    PH_MID(); \
    _Pragma("unroll") for (int i = 0; i < 4; i++) \
    _Pragma("unroll") for (int j = 0; j < 2; j++) { MM(4 + i, 2 + j, aS[i][0], bS[j][0]); MM(4 + i, 2 + j, aS[i][1], bS[j][1]); } \
    PH_END(); \
} while (0)

    const int NT = K >> 6;        // 64-wide K-tiles (even: K % 128 == 0)
    const int NI = NT >> 1;

    // prologue: buf0 <- kt0 (A0,A1,B0,B1); buf1 <- kt1 (A halves).
    STAGEM(gA0, 0); STAGEM(gA1, 1); STAGEM(gB0, 2); STAGEM(gB1, 3);
    STAGEM(gA0 + 128, 4); STAGEM(gA1 + 128, 5);
    asm volatile("s_waitcnt vmcnt(4)" ::: "memory");
    __builtin_amdgcn_s_barrier();

    for (int it = 0; it < NI; it++) {
        int k2 = 2 * it + 2; if (k2 > NT - 1) k2 = NT - 1;   // clamped tail prefetch
        int k3 = 2 * it + 3; if (k3 > NT - 1) k3 = NT - 1;
        DO4(0, 2 * it + 1, k2);
        DO4(1, k2, k3);
    }

    // drain all in-flight global_load_lds before workgroup retires
    asm volatile("s_waitcnt vmcnt(0)" ::: "memory");

#undef DO4
#undef PH_END
#undef PH_MID
#undef MM
#undef LDBf
#undef LDAf
#undef STAGEM
#undef GLDS

    // epilogue: C/D layout col=lane&15, row=(lane>>4)*4+reg (m89-verified)
#pragma unroll
    for (int i = 0; i < 8; i++)
#pragma unroll
        for (int j = 0; j < 4; j++)
#pragma unroll
            for (int r = 0; r < 4; r++) {
                int row = m0 + wr * 128 + i * 16 + lq * 4 + r;
                int col = n0 + wc * 64 + j * 16 + lrow;
                float v = acc[i][j][r];
                if (OUT_BF16) ((__bf16*)Cv)[(size_t)row * N + col] = (__bf16)v;
                else          ((float*)Cv)[(size_t)row * N + col] = v;
            }
}

// ---------------------------------------------------------------------------
// g_build_tok: one TOKEN per wave (both routed experts in one pass).
// Writes the EXTENDED row G[lt][0..KE):
//   cols [0,FF):       Gw[t][f] = w0*g0 + w1*g1  (bf16)
//   cols [FF,FF+128):  slot e*16+r = w0*ga0[r] (e==e0), w1*ga1[r] (e==e1), 0 else
// The extended row feeds the K=5760 fused down-projection GEMM (lora2 folded
// into the K axis — replaces the GA buffer + combine kernel entirely).
// ---------------------------------------------------------------------------
__global__ __launch_bounds__(256) void g_build_tok(const __bf16* __restrict__ base,
                                                   const __bf16* __restrict__ B1t,
                                                   const __bf16* __restrict__ B3t,
                                                   const __bf16* __restrict__ A2t,
                                                   const int* __restrict__ pair_e,
                                                   const float* __restrict__ pair_w,
                                                   __bf16* __restrict__ G,
                                                   int t0) {
    const int wave = threadIdx.x >> 6, lane = threadIdx.x & 63;
    const int lt = blockIdx.x * 4 + wave;     // local token in chunk
    const int t = t0 + lt;                    // global token
    const int e0 = pair_e[2 * t], e1 = pair_e[2 * t + 1];
    const float w0 = pair_w[2 * t], w1 = pair_w[2 * t + 1];
    const __bf16* brow = base + (size_t)lt * NALL;

    float ha1a[16], ha3a[16], ha1b[16], ha3b[16];
    {
        const bf16x8* pa = (const bf16x8*)(brow + 2 * FF + e0 * 32);
        const bf16x8* pb = (const bf16x8*)(brow + 2 * FF + e1 * 32);
        bf16x8 a0 = pa[0], a1 = pa[1], a2v = pa[2], a3v = pa[3];
        bf16x8 b0 = pb[0], b1v = pb[1], b2v = pb[2], b3v = pb[3];
#pragma unroll
        for (int r = 0; r < 8; r++) {
            ha1a[r] = (float)a0[r];  ha1a[8 + r] = (float)a1[r];
            ha3a[r] = (float)a2v[r]; ha3a[8 + r] = (float)a3v[r];
            ha1b[r] = (float)b0[r];  ha1b[8 + r] = (float)b1v[r];
            ha3b[r] = (float)b2v[r]; ha3b[8 + r] = (float)b3v[r];
        }
    }
    const __bf16* B1a = B1t + (size_t)e0 * FF * RR;
    const __bf16* B3a = B3t + (size_t)e0 * FF * RR;
    const __bf16* A2a = A2t + (size_t)e0 * FF * RR;
    const __bf16* B1b = B1t + (size_t)e1 * FF * RR;
    const __bf16* B3b = B3t + (size_t)e1 * FF * RR;
    const __bf16* A2b = A2t + (size_t)e1 * FF * RR;
    __bf16* Grow = G + (size_t)lt * KE;

    float ga0[16], ga1[16];
#pragma unroll
    for (int r = 0; r < 16; r++) { ga0[r] = 0.f; ga1[r] = 0.f; }

    for (int f = lane; f < FF; f += 64) {
        const size_t fo = (size_t)f * RR;
        const bf16x8* p;
        p = (const bf16x8*)(B1a + fo); bf16x8 b1l = p[0], b1h = p[1];
        p = (const bf16x8*)(B3a + fo); bf16x8 b3l = p[0], b3h = p[1];
        p = (const bf16x8*)(B1b + fo); bf16x8 c1l = p[0], c1h = p[1];
        p = (const bf16x8*)(B3b + fo); bf16x8 c3l = p[0], c3h = p[1];
        float bb1 = (float)brow[f], bb3 = (float)brow[FF + f];
        float u1a = bb1, u3a = bb3, u1b = bb1, u3b = bb3;
#pragma unroll
        for (int r = 0; r < 8; r++) {
            u1a += ha1a[r] * (float)b1l[r] + ha1a[8 + r] * (float)b1h[r];
            u3a += ha3a[r] * (float)b3l[r] + ha3a[8 + r] * (float)b3h[r];
            u1b += ha1b[r] * (float)c1l[r] + ha1b[8 + r] * (float)c1h[r];
            u3b += ha3b[r] * (float)c3l[r] + ha3b[8 + r] * (float)c3h[r];
        }
        float g0 = (u1a / (1.f + __expf(-u1a))) * u3a;
        float g1 = (u1b / (1.f + __expf(-u1b))) * u3b;
        Grow[f] = (__bf16)(w0 * g0 + w1 * g1);
        p = (const bf16x8*)(A2a + fo); bf16x8 a2l = p[0], a2h = p[1];
        p = (const bf16x8*)(A2b + fo); bf16x8 a4l = p[0], a4h = p[1];
#pragma unroll
        for (int r = 0; r < 8; r++) {
            ga0[r]     += g0 * (float)a2l[r];
            ga0[8 + r] += g0 * (float)a2h[r];
            ga1[r]     += g1 * (float)a4l[r];
            ga1[8 + r] += g1 * (float)a4h[r];
        }
    }
#pragma unroll
    for (int off = 32; off > 0; off >>= 1) {
#pragma unroll
        for (int r = 0; r < 16; r++) {
            ga0[r] += __shfl_down(ga0[r], off, 64);
            ga1[r] += __shfl_down(ga1[r], off, 64);
        }
    }
    if (lane == 0) {
        __bf16* tail = Grow + FF;
        bf16x8 z = {};
#pragma unroll
        for (int e = 0; e < EE; e++) {
            if (e == e0) {
                bf16x8 lo, hi;
#pragma unroll
                for (int r = 0; r < 8; r++) { lo[r] = (__bf16)(w0 * ga0[r]); hi[r] = (__bf16)(w0 * ga0[8 + r]); }
                ((bf16x8*)(tail + e * 16))[0] = lo; ((bf16x8*)(tail + e * 16))[1] = hi;
            } else if (e == e1) {
                bf16x8 lo, hi;
#pragma unroll
                for (int r = 0; r < 8; r++) { lo[r] = (__bf16)(w1 * ga1[r]); hi[r] = (__bf16)(w1 * ga1[8 + r]); }
                ((bf16x8*)(tail + e * 16))[0] = lo; ((bf16x8*)(tail + e * 16))[1] = hi;
            } else {
                ((bf16x8*)(tail + e * 16))[0] = z; ((bf16x8*)(tail + e * 16))[1] = z;
            }
        }
    }
}

// ---------------------------------------------------------------------------
extern "C" void kernel_launch(void* const* d_in, const int* in_sizes, int n_in,
                              void* d_out, int out_size, void* d_ws, size_t ws_size,
                              hipStream_t stream) {
    const float* x  = (const float*)d_in[0];
    const float* gw = (const float*)d_in[1];
    const float* W1 = (const float*)d_in[2];
    const float* W3 = (const float*)d_in[3];
    const float* W2 = (const float*)d_in[4];
    const float* A1 = (const float*)d_in[5];
    const float* B1 = (const float*)d_in[6];
    const float* A3 = (const float*)d_in[7];
    const float* B3 = (const float*)d_in[8];
    const float* A2 = (const float*)d_in[9];
    const float* B2 = (const float*)d_in[10];

    float* out    = (float*)d_out;                 // [T*D]
    float* logits = out + (size_t)TT * DD;         // [T*E]

    char* ws = (char*)d_ws;
    size_t off = 0;
    auto carve = [&](size_t bytes) {
        char* p = ws + off;
        off += (bytes + 255) & ~(size_t)255;
        return p;
    };
    auto pad = [](size_t b) { return (b + 255) & ~(size_t)255; };

    // ---- persistent small buffers ----
    __bf16* B1b   = (__bf16*)carve((size_t)EE * FF * RR * 2);   // 1.44 MB
    __bf16* B3b   = (__bf16*)carve((size_t)EE * FF * RR * 2);   // 1.44 MB
    __bf16* A2t   = (__bf16*)carve((size_t)EE * FF * RR * 2);   // 1.44 MB
    int*    pair_e = (int*)carve((size_t)NPAIR * 4);
    float*  pair_w = (float*)carve((size_t)NPAIR * 4);
    // WREG: W_all (W1|W3|A13 bf16, 47.2 MB) during GEMM1; after the last
    // GEMM1 chunk it is dead and W2ext (23.6 MB) is converted into it (full).
    char*   WREG  = carve((size_t)NALL * DD * 2);
    __bf16* W_all = (__bf16*)WREG;
    size_t base0 = off;

    // ---- mode/chunk selection (deterministic per call) ----
    int C = 0, full = 0;
    {
        const int cand[5] = {4096, 2048, 1024, 512, 256};
        for (int ci = 0; ci < 5; ci++) {
            int c = cand[ci];
            size_t need = base0 + pad((size_t)TT * KE * 2)
                        + pad((size_t)c * DD * 2) + pad((size_t)c * NALL * 2);
            if (need <= ws_size) { full = 1; C = c; break; }
        }
    }
    __bf16* Gbuf = nullptr; __bf16* base_c; __bf16* h_c; __bf16* W2e; __bf16* G_c = nullptr;
    if (full) {
        Gbuf   = (__bf16*)carve((size_t)TT * KE * 2);           // 94.4 MB extended-G
        h_c    = (__bf16*)carve((size_t)C * DD * 2);
        base_c = (__bf16*)carve((size_t)C * NALL * 2);
        W2e    = (__bf16*)WREG;                                 // converted post-GEMM1
    } else {
        // fallback: per-chunk pipeline (same extended-K fused GEMM2)
        W2e = (__bf16*)carve((size_t)DD * KE * 2);              // 23.6 MB
        C = 2048;
        while (C > 256) {
            size_t need = off + pad((size_t)C * DD * 2)
                        + pad((size_t)C * NALL * 2) + pad((size_t)C * KE * 2);
            if (need <= ws_size) break;
            C >>= 1;
        }
        h_c    = (__bf16*)carve((size_t)C * DD * 2);
        base_c = (__bf16*)carve((size_t)C * NALL * 2);
        G_c    = (__bf16*)carve((size_t)C * KE * 2);
    }

    // 1. weight converts (once)
    cvt_f32_bf16<<<1024, 256, 0, stream>>>(W1, W_all, FF * DD / 4);
    cvt_f32_bf16<<<1024, 256, 0, stream>>>(W3, W_all + (size_t)FF * DD, FF * DD / 4);
    cvt_A13<<<512, 256, 0, stream>>>(A1, A3, W_all + (size_t)2 * FF * DD);
    cvt_f32_bf16<<<512, 256, 0, stream>>>(B1, B1b, EE * FF * RR / 4);
    cvt_f32_bf16<<<512, 256, 0, stream>>>(B3, B3b, EE * FF * RR / 4);
    cvt_A2t<<<EE * RR * FF / 256, 256, 0, stream>>>(A2, A2t);
    if (!full) cvt_W2ext<<<2048, 256, 0, stream>>>(W2, B2, W2e);

    // 2. router (fp32) — writes logits output + pair routing
    router_k<<<TT / 4, 256, 0, stream>>>(x, gw, logits, pair_e, pair_w);

    // 3-4. chunked: x convert + up-projection + gate build (extended G rows)
    for (int t0 = 0; t0 < TT; t0 += C) {
        cvt_f32_bf16<<<1024, 256, 0, stream>>>(x + (size_t)t0 * DD, h_c, C * DD / 4);
        gemm256<1><<<dim3(C / 256, NALL / 256), 512, 0, stream>>>(
            h_c, W_all, base_c, C, NALL, DD);
        __bf16* Gp = full ? (Gbuf + (size_t)t0 * KE) : G_c;
        g_build_tok<<<C / 4, 256, 0, stream>>>(base_c, B1b, B3b, A2t, pair_e, pair_w, Gp, t0);
        if (!full) {
            gemm256<0><<<dim3(C / 256, DD / 256), 512, 0, stream>>>(
                G_c, W2e, out + (size_t)t0 * DD, C, DD, KE);
        }
    }

    // 5. one-shot fused down-projection (K=5760: W2 + per-token masked lora2)
    if (full) {
        cvt_W2ext<<<2048, 256, 0, stream>>>(W2, B2, W2e);   // into WREG (W_all dead)
        gemm256<0><<<dim3(TT / 256, DD / 256), 512, 0, stream>>>(
            Gbuf, W2e, out, TT, DD, KE);
    }
}

// Round 8
// 1227.123 us; speedup vs baseline: 6.5095x; 1.0130x over previous
//
#include <hip/hip_runtime.h>
#include <hip/hip_bf16.h>
#include <stdint.h>

// Problem constants
#define TT   8192      // tokens = B*S
#define DD   2048      // d_model
#define FF   5632      // ffn hidden
#define EE   8         // experts
#define RR   16        // lora rank
#define NALL 11520     // F + F + E*2R = 5632+5632+256
#define KE   5760      // FF + EE*RR: extended K for fused down-projection
#define NPAIR 16384    // T * TOPK

typedef float  f32x4  __attribute__((ext_vector_type(4)));
typedef __bf16 bf16x8 __attribute__((ext_vector_type(8)));
typedef __bf16 bf16x4 __attribute__((ext_vector_type(4)));
typedef __bf16 bf16x2 __attribute__((ext_vector_type(2)));

#define AS1CAST(p) ((__attribute__((address_space(1))) void*)(p))
#define AS3CAST(p) ((__attribute__((address_space(3))) void*)(p))

#if defined(__has_builtin)
# if __has_builtin(__builtin_amdgcn_fdot2_f32_bf16)
#  define HAVE_DOT2 1
# endif
#endif
#ifndef HAVE_DOT2
# define HAVE_DOT2 0
#endif

// ---------------------------------------------------------------------------
// f32 -> bf16 convert (float4 vectorized, grid-stride)
// ---------------------------------------------------------------------------
__global__ __launch_bounds__(256) void cvt_f32_bf16(const float* __restrict__ src,
                                                    __bf16* __restrict__ dst, int n4) {
    int stride = gridDim.x * 256;
    for (int i = blockIdx.x * 256 + threadIdx.x; i < n4; i += stride) {
        float4 v = ((const float4*)src)[i];
        bf16x4 o = {(__bf16)v.x, (__bf16)v.y, (__bf16)v.z, (__bf16)v.w};
        ((bf16x4*)dst)[i] = o;
    }
}

// ---------------------------------------------------------------------------
// cvt_all: one grid-stride kernel for ALL weight preprocessing:
//   [0, Q1)        : W1 -> W_all[0..FF*DD)            (float4 quads)
//   [Q1, 2Q1)      : W3 -> W_all[FF*DD..2*FF*DD)
//   [2Q1, 2Q1+QA)  : A1/A3 gather -> W_all rows [2FF*DD..), row j=e*32+l
//   [.., +QT)      : fused expert table Tbl[e][f][48] = B1[e][f][:16] |
//                    B3[e][f][:16] | A2[e][:][f] (transposed), bf16x8 groups
// ---------------------------------------------------------------------------
__global__ __launch_bounds__(256) void cvt_all(const float* __restrict__ W1,
                                               const float* __restrict__ W3,
                                               const float* __restrict__ A1,
                                               const float* __restrict__ A3,
                                               const float* __restrict__ B1,
                                               const float* __restrict__ B3,
                                               const float* __restrict__ A2,
                                               __bf16* __restrict__ W_all,
                                               __bf16* __restrict__ Tbl) {
    const int Q1 = FF * DD / 4;            // 2883584
    const int QA = 256 * (DD / 4);         // 131072
    const int QT = EE * FF * 6;            // 270336
    const int NTOT = 2 * Q1 + QA + QT;
    int stride = gridDim.x * 256;
    for (int i = blockIdx.x * 256 + threadIdx.x; i < NTOT; i += stride) {
        if (i < 2 * Q1) {
            const float* s = (i < Q1) ? (W1 + (size_t)i * 4) : (W3 + (size_t)(i - Q1) * 4);
            float4 v = *(const float4*)s;
            bf16x4 o = {(__bf16)v.x, (__bf16)v.y, (__bf16)v.z, (__bf16)v.w};
            ((bf16x4*)W_all)[i] = o;
        } else if (i < 2 * Q1 + QA) {
            int q = i - 2 * Q1;
            int col4 = q & 511;            // DD/4 = 512
            int j = q >> 9;                // row 0..255
            int e = j >> 5, l = j & 31;
            const float* src = (l < 16) ? (A1 + (size_t)(e * 16 + l) * DD)
                                        : (A3 + (size_t)(e * 16 + (l - 16)) * DD);
            float4 v = ((const float4*)src)[col4];
            bf16x4 o = {(__bf16)v.x, (__bf16)v.y, (__bf16)v.z, (__bf16)v.w};
            ((bf16x4*)(W_all + (size_t)2 * FF * DD))[q] = o;
        } else {
            int q = i - 2 * Q1 - QA;
            int c = q % 6;
            int fe = q / 6;
            int f = fe % FF, e = fe / FF;
            __bf16* d = Tbl + (size_t)fe * 48 + c * 8;
            bf16x8 o;
            if (c < 4) {
                const float* s = ((c < 2) ? B1 : B3) + ((size_t)e * FF + f) * RR + (c & 1) * 8;
                float4 a = ((const float4*)s)[0], b = ((const float4*)s)[1];
                o[0] = (__bf16)a.x; o[1] = (__bf16)a.y; o[2] = (__bf16)a.z; o[3] = (__bf16)a.w;
                o[4] = (__bf16)b.x; o[5] = (__bf16)b.y; o[6] = (__bf16)b.z; o[7] = (__bf16)b.w;
            } else {
                int r0 = (c - 4) * 8;
                const float* s = A2 + ((size_t)e * RR + r0) * FF + f;
#pragma unroll
                for (int j = 0; j < 8; j++) o[j] = (__bf16)s[(size_t)j * FF];
            }
            *(bf16x8*)d = o;
        }
    }
}

// W2ext [D][KE] bf16: row d = [W2[d][0..FF) | B2[e][d][r] for e*16+r in 0..128)
__global__ __launch_bounds__(256) void cvt_W2ext(const float* __restrict__ W2,
                                                 const float* __restrict__ B2,
                                                 __bf16* __restrict__ dst) {
    const int n4 = DD * KE / 4;
    int stride = gridDim.x * 256;
    for (int i = blockIdx.x * 256 + threadIdx.x; i < n4; i += stride) {
        int j = (i % (KE / 4)) * 4;           // col (multiple of 4)
        int d = i / (KE / 4);
        float4 v;
        if (j < FF) {
            v = *(const float4*)(W2 + (size_t)d * FF + j);
        } else {
            int o = j - FF;                   // 0..127, multiple of 4 -> same expert block
            int e = o >> 4, r = o & 15;
            const float* b = B2 + ((size_t)e * DD + d) * RR + r;
            v.x = b[0]; v.y = b[1]; v.z = b[2]; v.w = b[3];
        }
        bf16x4 o4 = {(__bf16)v.x, (__bf16)v.y, (__bf16)v.z, (__bf16)v.w};
        ((bf16x4*)dst)[i] = o4;
    }
}

// ---------------------------------------------------------------------------
// Router: logits (fp32, output #2), top-2 renormalized weights per token
// ---------------------------------------------------------------------------
__global__ __launch_bounds__(256) void router_k(const float* __restrict__ x,
                                                const float* __restrict__ gw,
                                                float* __restrict__ logits,
                                                int* __restrict__ pair_e,
                                                float* __restrict__ pair_w) {
    int t = blockIdx.x * 4 + (threadIdx.x >> 6);
    int lane = threadIdx.x & 63;
    const float* xr = x + (size_t)t * DD;
    float acc[EE];
#pragma unroll
    for (int e = 0; e < EE; e++) acc[e] = 0.f;
    for (int d = lane; d < DD; d += 64) {
        float xv = xr[d];
#pragma unroll
        for (int e = 0; e < EE; e++) acc[e] += xv * gw[e * DD + d];
    }
#pragma unroll
    for (int off = 32; off > 0; off >>= 1) {
#pragma unroll
        for (int e = 0; e < EE; e++) acc[e] += __shfl_down(acc[e], off, 64);
    }
    if (lane == 0) {
        float mx = acc[0];
#pragma unroll
        for (int e = 1; e < EE; e++) mx = fmaxf(mx, acc[e]);
        float p[EE];
#pragma unroll
        for (int e = 0; e < EE; e++) p[e] = __expf(acc[e] - mx);
        int e0 = 0;
#pragma unroll
        for (int e = 1; e < EE; e++) if (p[e] > p[e0]) e0 = e;
        int e1 = (e0 == 0) ? 1 : 0;
#pragma unroll
        for (int e = 0; e < EE; e++) if (e != e0 && p[e] > p[e1]) e1 = e;
        float s = p[e0] + p[e1];
        pair_e[2 * t] = e0;     pair_e[2 * t + 1] = e1;
        pair_w[2 * t] = p[e0] / s; pair_w[2 * t + 1] = p[e1] / s;
#pragma unroll
        for (int e = 0; e < EE; e++) logits[(size_t)t * EE + e] = acc[e];
    }
}

// ---------------------------------------------------------------------------
// 256x256-tile 8-phase bf16 GEMM, B^T layout: C[M,N] = A[M,K] * B[N,K]^T.
// M,N multiples of 256; K multiple of 128.  512 threads = 8 waves (2Mx4N).
// Swizzle: round-3 form (measured fastest): byte ^= ((row>>2)&1)<<5 on both
// the staging global source and the ds_read address.
// Counted vmcnt(4) once per K-tile; epilogue drains vmcnt to 0.
// ---------------------------------------------------------------------------
template <int OUT_BF16>
__global__ __launch_bounds__(512, 2) void gemm256(const __bf16* __restrict__ A,
                                                  const __bf16* __restrict__ B,
                                                  void* __restrict__ Cv,
                                                  int M, int N, int K) {
    __shared__ __align__(16) __bf16 lds[8][8192];   // [buf*4 + mat*2 + half][128*64]
    char* const sbase = (char*)&lds[0][0];
    const int tid = threadIdx.x;
    const int w = tid >> 6, lane = tid & 63;
    const int lrow = lane & 15, lq = lane >> 4;
    const int wr = w >> 2, wc = w & 3;

    // bijective XCD swizzle (m204)
    const int gx = gridDim.x;
    const int nwg = gx * gridDim.y;
    const int orig = blockIdx.x + blockIdx.y * gx;
    const int q8 = nwg >> 3, r8 = nwg & 7;
    const int xcd = orig & 7, sid = orig >> 3;
    const int nid = (xcd < r8 ? xcd * (q8 + 1) : r8 * (q8 + 1) + (xcd - r8) * q8) + sid;
    const int m0 = (nid % gx) * 256;
    const int n0 = (nid / gx) * 256;

    const size_t ldb = (size_t)K * 2;               // bytes per row
    const int rq0 = w * 16 + (lane >> 3);
    const int cbs = ((lane & 7) * 16) ^ (((rq0 >> 2) & 1) << 5);
    const char* gA0 = (const char*)A + (size_t)(m0 + rq0) * ldb + cbs;   // A half0
    const char* gA1 = gA0 + (size_t)128 * ldb;                            // A half1
    const char* gB0 = (const char*)B + (size_t)(n0 + rq0) * ldb + cbs;
    const char* gB1 = gB0 + (size_t)128 * ldb;
    const int wseg = w * 2048;

    const int sb = ((lrow >> 2) & 1) << 5;
    const int aoff = lrow * 128 + ((lq * 16) ^ sb);
    const int boff = ((wc & 1) * 64 + lrow) * 128 + ((lq * 16) ^ sb);
    const int abuf = wr;             // A half this wave reads
    const int bbuf = 2 + (wc >> 1);  // B half this wave reads

    f32x4 acc[8][4] = {};
    bf16x8 aR[4][2], aS[4][2], bR[2][2], bS[2][2];

#define GLDS(gp, lo) __builtin_amdgcn_global_load_lds(AS1CAST((void*)(gp)), AS3CAST(sbase + (lo)), 16, 0, 0)
#define STAGEM(gp, bufmh) do { const char* _g = (gp); \
        GLDS(_g, (bufmh) * 16384 + wseg); \
        GLDS(_g + 8 * ldb, (bufmh) * 16384 + wseg + 1024); } while (0)
#define LDAf(c, i, ks) (*(const bf16x8*)(sbase + ((c) * 4 + abuf) * 16384 + aoff + (i) * 2048 + (ks) * 64))
#define LDBf(c, j, ks) (*(const bf16x8*)(sbase + ((c) * 4 + bbuf) * 16384 + boff + (j) * 2048 + (ks) * 64))
#define MM(i, j, fa, fb) acc[i][j] = __builtin_amdgcn_mfma_f32_16x16x32_bf16(fa, fb, acc[i][j], 0, 0, 0)
#define PH_MID() do { __builtin_amdgcn_s_barrier(); \
        asm volatile("s_waitcnt lgkmcnt(0)" ::: "memory"); \
        __builtin_amdgcn_sched_barrier(0); \
        __builtin_amdgcn_s_setprio(1); } while (0)
#define PH_END() do { __builtin_amdgcn_s_setprio(0); \
        __builtin_amdgcn_s_barrier(); } while (0)

#define DO4(c, kBC, kAC) do { \
    _Pragma("unroll") for (int i = 0; i < 4; i++) { aR[i][0] = LDAf(c, i, 0); aR[i][1] = LDAf(c, i, 1); } \
    _Pragma("unroll") for (int j = 0; j < 2; j++) { bR[j][0] = LDBf(c, j, 0); bR[j][1] = LDBf(c, j, 1); } \
    STAGEM(gB0 + (size_t)(kBC) * 128, ((c) ^ 1) * 4 + 2); \
    PH_MID(); \
    _Pragma("unroll") for (int i = 0; i < 4; i++) \
    _Pragma("unroll") for (int j = 0; j < 2; j++) { MM(i, j, aR[i][0], bR[j][0]); MM(i, j, aR[i][1], bR[j][1]); } \
    PH_END(); \
    _Pragma("unroll") for (int i = 0; i < 4; i++) { aS[i][0] = LDAf(c, 4 + i, 0); aS[i][1] = LDAf(c, 4 + i, 1); } \
    STAGEM(gB1 + (size_t)(kBC) * 128, ((c) ^ 1) * 4 + 3); \
    PH_MID(); \
    _Pragma("unroll") for (int i = 0; i < 4; i++) \
    _Pragma("unroll") for (int j = 0; j < 2; j++) { MM(4 + i, j, aS[i][0], bR[j][0]); MM(4 + i, j, aS[i][1], bR[j][1]); } \
    PH_END(); \
    _Pragma("unroll") for (int j = 0; j < 2; j++) { bS[j][0] = LDBf(c, 2 + j, 0); bS[j][1] = LDBf(c, 2 + j, 1); } \
    STAGEM(gA0 + (size_t)(kAC) * 128, (c) * 4 + 0); \
    PH_MID(); \
    _Pragma("unroll") for (int i = 0; i < 4; i++) \
    _Pragma("unroll") for (int j = 0; j < 2; j++) { MM(i, 2 + j, aR[i][0], bS[j][0]); MM(i, 2 + j, aR[i][1], bS[j][1]); } \
    PH_END(); \
    STAGEM(gA1 + (size_t)(kAC) * 128, (c) * 4 + 1); \
    asm volatile("s_waitcnt vmcnt(4)" ::: "memory"); \
    PH_MID(); \
    _Pragma("unroll") for (int i = 0; i < 4; i++) \
    _Pragma("unroll") for (int j = 0; j < 2; j++) { MM(4 + i, 2 + j, aS[i][0], bS[j][0]); MM(4 + i, 2 + j, aS[i][1], bS[j][1]); } \
    PH_END(); \
} while (0)

    const int NT = K >> 6;        // 64-wide K-tiles (even: K % 128 == 0)
    const int NI = NT >> 1;

    STAGEM(gA0, 0); STAGEM(gA1, 1); STAGEM(gB0, 2); STAGEM(gB1, 3);
    STAGEM(gA0 + 128, 4); STAGEM(gA1 + 128, 5);
    asm volatile("s_waitcnt vmcnt(4)" ::: "memory");
    __builtin_amdgcn_s_barrier();

    for (int it = 0; it < NI; it++) {
        int k2 = 2 * it + 2; if (k2 > NT - 1) k2 = NT - 1;   // clamped tail prefetch
        int k3 = 2 * it + 3; if (k3 > NT - 1) k3 = NT - 1;
        DO4(0, 2 * it + 1, k2);
        DO4(1, k2, k3);
    }

    // drain all in-flight global_load_lds before workgroup retires
    asm volatile("s_waitcnt vmcnt(0)" ::: "memory");

#undef DO4
#undef PH_END
#undef PH_MID
#undef MM
#undef LDBf
#undef LDAf
#undef STAGEM
#undef GLDS

    // epilogue: C/D layout col=lane&15, row=(lane>>4)*4+reg (m89-verified)
#pragma unroll
    for (int i = 0; i < 8; i++)
#pragma unroll
        for (int j = 0; j < 4; j++)
#pragma unroll
            for (int r = 0; r < 4; r++) {
                int row = m0 + wr * 128 + i * 16 + lq * 4 + r;
                int col = n0 + wc * 64 + j * 16 + lrow;
                float v = acc[i][j][r];
                if (OUT_BF16) ((__bf16*)Cv)[(size_t)row * N + col] = (__bf16)v;
                else          ((float*)Cv)[(size_t)row * N + col] = v;
            }
}

// ---------------------------------------------------------------------------
// dot8: bf16x8 . bf16x8 + c.  Uses v_dot2_f32_bf16 when available (1 inst per
// bf16 pair vs 2 cvt + 2 fma), scalar-convert fallback otherwise.
// ---------------------------------------------------------------------------
__device__ __forceinline__ float dot8(bf16x8 a, bf16x8 b, float c) {
#if HAVE_DOT2
    const bf16x2* ap = (const bf16x2*)&a;
    const bf16x2* bp = (const bf16x2*)&b;
#pragma unroll
    for (int j = 0; j < 4; j++) c = __builtin_amdgcn_fdot2_f32_bf16(ap[j], bp[j], c, false);
#else
#pragma unroll
    for (int j = 0; j < 8; j++) c += (float)a[j] * (float)b[j];
#endif
    return c;
}

// ---------------------------------------------------------------------------
// g_build_tok: one TOKEN per wave (both routed experts in one pass).
// Reads the FUSED table Tbl[e][f][48] = B1|B3|A2t rows (2 base addrs +
// immediate offsets, replaces 6 separate address streams).
// Writes the EXTENDED row G[lt][0..KE):
//   cols [0,FF):       Gw[t][f] = w0*g0 + w1*g1  (bf16)
//   cols [FF,FF+128):  slot e*16+r = w_k*ga_k[r] for the routed experts, 0 else
// ---------------------------------------------------------------------------
__global__ __launch_bounds__(256) void g_build_tok(const __bf16* __restrict__ base,
                                                   const __bf16* __restrict__ Tbl,
                                                   const int* __restrict__ pair_e,
                                                   const float* __restrict__ pair_w,
                                                   __bf16* __restrict__ G,
                                                   int t0) {
    const int wave = threadIdx.x >> 6, lane = threadIdx.x & 63;
    const int lt = blockIdx.x * 4 + wave;     // local token in chunk
    const int t = t0 + lt;                    // global token
    const int e0 = pair_e[2 * t], e1 = pair_e[2 * t + 1];
    const float w0 = pair_w[2 * t], w1 = pair_w[2 * t + 1];
    const __bf16* brow = base + (size_t)lt * NALL;

    // ha fragments (broadcast loads; kept in bf16 on the dot2 path)
    const bf16x8* pa = (const bf16x8*)(brow + 2 * FF + e0 * 32);
    const bf16x8* pb = (const bf16x8*)(brow + 2 * FF + e1 * 32);
    bf16x8 h1a0 = pa[0], h1a1 = pa[1], h3a0 = pa[2], h3a1 = pa[3];
    bf16x8 h1b0 = pb[0], h1b1 = pb[1], h3b0 = pb[2], h3b1 = pb[3];

    const char* Ta = (const char*)Tbl + (size_t)e0 * FF * 96;
    const char* Tb = (const char*)Tbl + (size_t)e1 * FF * 96;
    __bf16* Grow = G + (size_t)lt * KE;

    float ga0[16], ga1[16];
#pragma unroll
    for (int r = 0; r < 16; r++) { ga0[r] = 0.f; ga1[r] = 0.f; }

#pragma unroll 2
    for (int f = lane; f < FF; f += 64) {
        const char* ra = Ta + (size_t)f * 96;
        const char* rb = Tb + (size_t)f * 96;
        bf16x8 b1a0 = *(const bf16x8*)(ra);
        bf16x8 b1a1 = *(const bf16x8*)(ra + 16);
        bf16x8 b3a0 = *(const bf16x8*)(ra + 32);
        bf16x8 b3a1 = *(const bf16x8*)(ra + 48);
        bf16x8 a2a0 = *(const bf16x8*)(ra + 64);
        bf16x8 a2a1 = *(const bf16x8*)(ra + 80);
        bf16x8 b1b0 = *(const bf16x8*)(rb);
        bf16x8 b1b1 = *(const bf16x8*)(rb + 16);
        bf16x8 b3b0 = *(const bf16x8*)(rb + 32);
        bf16x8 b3b1 = *(const bf16x8*)(rb + 48);
        bf16x8 a2b0 = *(const bf16x8*)(rb + 64);
        bf16x8 a2b1 = *(const bf16x8*)(rb + 80);

        float bb1 = (float)brow[f];
        float bb3 = (float)brow[FF + f];
        float u1a = dot8(h1a1, b1a1, dot8(h1a0, b1a0, bb1));
        float u3a = dot8(h3a1, b3a1, dot8(h3a0, b3a0, bb3));
        float u1b = dot8(h1b1, b1b1, dot8(h1b0, b1b0, bb1));
        float u3b = dot8(h3b1, b3b1, dot8(h3b0, b3b0, bb3));

        float g0 = (u1a / (1.f + __expf(-u1a))) * u3a;
        float g1 = (u1b / (1.f + __expf(-u1b))) * u3b;
        Grow[f] = (__bf16)(w0 * g0 + w1 * g1);
#pragma unroll
        for (int r = 0; r < 8; r++) {
            ga0[r]     += g0 * (float)a2a0[r];
            ga0[8 + r] += g0 * (float)a2a1[r];
            ga1[r]     += g1 * (float)a2b0[r];
            ga1[8 + r] += g1 * (float)a2b1[r];
        }
    }
#pragma unroll
    for (int off = 32; off > 0; off >>= 1) {
#pragma unroll
        for (int r = 0; r < 16; r++) {
            ga0[r] += __shfl_down(ga0[r], off, 64);
            ga1[r] += __shfl_down(ga1[r], off, 64);
        }
    }
    if (lane == 0) {
        __bf16* tail = Grow + FF;
        bf16x8 z = {};
#pragma unroll
        for (int e = 0; e < EE; e++) {
            if (e == e0) {
                bf16x8 lo, hi;
#pragma unroll
                for (int r = 0; r < 8; r++) { lo[r] = (__bf16)(w0 * ga0[r]); hi[r] = (__bf16)(w0 * ga0[8 + r]); }
                ((bf16x8*)(tail + e * 16))[0] = lo; ((bf16x8*)(tail + e * 16))[1] = hi;
            } else if (e == e1) {
                bf16x8 lo, hi;
#pragma unroll
                for (int r = 0; r < 8; r++) { lo[r] = (__bf16)(w1 * ga1[r]); hi[r] = (__bf16)(w1 * ga1[8 + r]); }
                ((bf16x8*)(tail + e * 16))[0] = lo; ((bf16x8*)(tail + e * 16))[1] = hi;
            } else {
                ((bf16x8*)(tail + e * 16))[0] = z; ((bf16x8*)(tail + e * 16))[1] = z;
            }
        }
    }
}

// ---------------------------------------------------------------------------
extern "C" void kernel_launch(void* const* d_in, const int* in_sizes, int n_in,
                              void* d_out, int out_size, void* d_ws, size_t ws_size,
                              hipStream_t stream) {
    const float* x  = (const float*)d_in[0];
    const float* gw = (const float*)d_in[1];
    const float* W1 = (const float*)d_in[2];
    const float* W3 = (const float*)d_in[3];
    const float* W2 = (const float*)d_in[4];
    const float* A1 = (const float*)d_in[5];
    const float* B1 = (const float*)d_in[6];
    const float* A3 = (const float*)d_in[7];
    const float* B3 = (const float*)d_in[8];
    const float* A2 = (const float*)d_in[9];
    const float* B2 = (const float*)d_in[10];

    float* out    = (float*)d_out;                 // [T*D]
    float* logits = out + (size_t)TT * DD;         // [T*E]

    char* ws = (char*)d_ws;
    size_t off = 0;
    auto carve = [&](size_t bytes) {
        char* p = ws + off;
        off += (bytes + 255) & ~(size_t)255;
        return p;
    };
    auto pad = [](size_t b) { return (b + 255) & ~(size_t)255; };

    // ---- persistent small buffers ----
    __bf16* Tbl   = (__bf16*)carve((size_t)EE * FF * 48 * 2);   // 4.33 MB fused B1|B3|A2t
    int*    pair_e = (int*)carve((size_t)NPAIR * 4);
    float*  pair_w = (float*)carve((size_t)NPAIR * 4);
    // WREG: W_all (W1|W3|A13 bf16, 47.2 MB) during GEMM1; after the last
    // GEMM1 chunk it is dead and W2ext (23.6 MB) is converted into it (full).
    char*   WREG  = carve((size_t)NALL * DD * 2);
    __bf16* W_all = (__bf16*)WREG;
    size_t base0 = off;

    // ---- mode/chunk selection (deterministic per call) ----
    int C = 0, full = 0;
    {
        const int cand[5] = {4096, 2048, 1024, 512, 256};
        for (int ci = 0; ci < 5; ci++) {
            int c = cand[ci];
            size_t need = base0 + pad((size_t)TT * KE * 2)
                        + pad((size_t)c * DD * 2) + pad((size_t)c * NALL * 2);
            if (need <= ws_size) { full = 1; C = c; break; }
        }
    }
    __bf16* Gbuf = nullptr; __bf16* base_c; __bf16* h_c; __bf16* W2e; __bf16* G_c = nullptr;
    if (full) {
        Gbuf   = (__bf16*)carve((size_t)TT * KE * 2);           // 94.4 MB extended-G
        h_c    = (__bf16*)carve((size_t)C * DD * 2);
        base_c = (__bf16*)carve((size_t)C * NALL * 2);
        W2e    = (__bf16*)WREG;                                 // converted post-GEMM1
    } else {
        // fallback: per-chunk pipeline (same extended-K fused GEMM2)
        W2e = (__bf16*)carve((size_t)DD * KE * 2);              // 23.6 MB
        C = 2048;
        while (C > 256) {
            size_t need = off + pad((size_t)C * DD * 2)
                        + pad((size_t)C * NALL * 2) + pad((size_t)C * KE * 2);
            if (need <= ws_size) break;
            C >>= 1;
        }
        h_c    = (__bf16*)carve((size_t)C * DD * 2);
        base_c = (__bf16*)carve((size_t)C * NALL * 2);
        G_c    = (__bf16*)carve((size_t)C * KE * 2);
    }

    // 1. all weight preprocessing in one dispatch
    cvt_all<<<4096, 256, 0, stream>>>(W1, W3, A1, A3, B1, B3, A2, W_all, Tbl);
    if (!full) cvt_W2ext<<<2048, 256, 0, stream>>>(W2, B2, W2e);

    // 2. router (fp32) — writes logits output + pair routing
    router_k<<<TT / 4, 256, 0, stream>>>(x, gw, logits, pair_e, pair_w);

    // 3-4. chunked: x convert + up-projection + gate build (extended G rows)
    for (int t0 = 0; t0 < TT; t0 += C) {
        cvt_f32_bf16<<<1024, 256, 0, stream>>>(x + (size_t)t0 * DD, h_c, C * DD / 4);
        gemm256<1><<<dim3(C / 256, NALL / 256), 512, 0, stream>>>(
            h_c, W_all, base_c, C, NALL, DD);
        __bf16* Gp = full ? (Gbuf + (size_t)t0 * KE) : G_c;
        g_build_tok<<<C / 4, 256, 0, stream>>>(base_c, Tbl, pair_e, pair_w, Gp, t0);
        if (!full) {
            gemm256<0><<<dim3(C / 256, DD / 256), 512, 0, stream>>>(
                G_c, W2e, out + (size_t)t0 * DD, C, DD, KE);
        }
    }

    // 5. one-shot fused down-projection (K=5760: W2 + per-token masked lora2)
    if (full) {
        cvt_W2ext<<<2048, 256, 0, stream>>>(W2, B2, W2e);   // into WREG (W_all dead)
        gemm256<0><<<dim3(TT / 256, DD / 256), 512, 0, stream>>>(
            Gbuf, W2e, out, TT, DD, KE);
    }
}